// Round 17
// baseline (216.264 us; speedup 1.0000x reference)
//
#include <hip/hip_runtime.h>
#include <hip/hip_bf16.h>

typedef unsigned short u16;
typedef __attribute__((ext_vector_type(8))) short short8;
typedef __attribute__((ext_vector_type(4))) float f32x4;
typedef __attribute__((ext_vector_type(16))) float f32x16;
typedef __attribute__((ext_vector_type(2))) unsigned int u32x2;

#define MODEL 768
// 1/sqrt(128) * log2(e): exp(s/sqrt(128)) == exp2(s * SCALE2)
#define SCALE2 0.1275174137f

__device__ __forceinline__ float bf2f(u16 u) {
  unsigned int x = ((unsigned int)u) << 16;
  return __uint_as_float(x);
}
__device__ __forceinline__ u16 f2bf(float f) {
  unsigned int x = __float_as_uint(f);
  unsigned int r = (x + 0x7FFFu + ((x >> 16) & 1u)) >> 16;
  return (u16)r;
}
__device__ __forceinline__ void lds_ld16(const u16* g, u16* l) {
  __builtin_amdgcn_global_load_lds((const __attribute__((address_space(1))) void*)g,
                                   (__attribute__((address_space(3))) void*)l, 16, 0, 0);
}
__device__ __forceinline__ unsigned int cvtpk_bf16(float lo, float hi_) {
  unsigned int r;
  asm("v_cvt_pk_bf16_f32 %0, %1, %2" : "=v"(r) : "v"(lo), "v"(hi_));
  return r;
}

// ---------------------------------------------------------------------------
// Kernel 1: x f32 -> bf16 (786432 float4 units) AND zero accO/accL.
// ---------------------------------------------------------------------------
__global__ __launch_bounds__(256) void r17_cvt_x(const float* __restrict__ x,
                                                 u16* __restrict__ xb,
                                                 float* __restrict__ accZ) {
  int i = blockIdx.x * 256 + threadIdx.x;
  if (i < 786432) {
    float4 v = ((const float4*)x)[i];
    ushort4 o;
    o.x = f2bf(v.x); o.y = f2bf(v.y); o.z = f2bf(v.z); o.w = f2bf(v.w);
    ((ushort4*)xb)[i] = o;
  } else if (i < 786432 + 792576) {
    float4 z = {0.0f, 0.0f, 0.0f, 0.0f};
    ((float4*)accZ)[i - 786432] = z;
  }
}

// ---------------------------------------------------------------------------
// GEMM QKV + FUSED normrope epilogue.
// Tile = 128 rows x 1 full head (blockIdx.y) x matrix bz.  Main loop is the
// r12/r16-proven BK=32 structure.  Epilogue:
//   bz<2 (Q,K): stage acc f32 -> LDS (2 groups of 64 rows), per-row RMS
//               (4 thr/row, shfl reduce) + rotary pair (d, d+64), bf16 out.
//   bz=2 (V):   in-register lambda-mix with vres + out1 = vres passthrough.
// ---------------------------------------------------------------------------
__global__ __launch_bounds__(256) void r17_gemm_qkv(const u16* __restrict__ A,
                                                    const float* __restrict__ W0,
                                                    const float* __restrict__ W1,
                                                    const float* __restrict__ W2,
                                                    u16* __restrict__ C0,
                                                    u16* __restrict__ C1,
                                                    u16* __restrict__ C2,
                                                    const float* __restrict__ vres,
                                                    const float* __restrict__ lambp,
                                                    const int* __restrict__ pos,
                                                    float* __restrict__ out1) {
  const int bz = blockIdx.z;
  const float* W = (bz == 0) ? W0 : (bz == 1) ? W1 : W2;
  u16* C = (bz == 0) ? C0 : (bz == 1) ? C1 : C2;
  __shared__ u16 As[128 * 32];
  __shared__ u16 Bs[128 * 32];
  __shared__ float fs[64][129];   // epilogue row-staging (Q/K only)
  const int tid = threadIdx.x;
  const int w = tid >> 6, l = tid & 63;
  const int lr = l & 15, lg = l >> 4;
  const int m0 = blockIdx.x * 128, n0 = blockIdx.y * 128;
  const int wr = (w >> 1) * 64, wc = (w & 1) * 64;
  const int sr = w * 32 + (l >> 2);
  const int sc = (l & 3) * 8;
  const int qrow = tid >> 1;
  const int qoff = (tid & 1) * 16;
  f32x4 acc[4][4] = {};
  for (int k0 = 0; k0 < 768; k0 += 32) {
    __syncthreads();
    lds_ld16(A + (size_t)(m0 + sr) * 768 + k0 + sc, As + (w * 2 + 0) * 512);
    lds_ld16(A + (size_t)(m0 + sr + 16) * 768 + k0 + sc, As + (w * 2 + 1) * 512);
    {
      const float* wp = W + (size_t)(n0 + qrow) * 768 + k0 + qoff;
      u16* bp = Bs + qrow * 32 + qoff;
#pragma unroll
      for (int q = 0; q < 4; q++) {
        float4 f = ((const float4*)wp)[q];
        ushort4 b;
        b.x = f2bf(f.x); b.y = f2bf(f.y); b.z = f2bf(f.z); b.w = f2bf(f.w);
        *(ushort4*)(bp + q * 4) = b;
      }
    }
    __syncthreads();
    short8 af[4], bfr[4];
#pragma unroll
    for (int mr = 0; mr < 4; mr++) af[mr] = *(const short8*)(As + (wr + mr * 16 + lr) * 32 + lg * 8);
#pragma unroll
    for (int nc = 0; nc < 4; nc++) bfr[nc] = *(const short8*)(Bs + (wc + nc * 16 + lr) * 32 + lg * 8);
#pragma unroll
    for (int mr = 0; mr < 4; mr++)
#pragma unroll
      for (int nc = 0; nc < 4; nc++)
        acc[mr][nc] = __builtin_amdgcn_mfma_f32_16x16x32_bf16(af[mr], bfr[nc], acc[mr][nc], 0, 0, 0);
  }

  if (bz == 2) {
    // ---- V path: v = (1-lamb)*acc + lamb*vres ; out1 = vres ----
    const float lm = *lambp;
#pragma unroll
    for (int mr = 0; mr < 4; mr++)
#pragma unroll
      for (int nc = 0; nc < 4; nc++)
#pragma unroll
        for (int ri = 0; ri < 4; ri++) {
          int row = m0 + wr + mr * 16 + lg * 4 + ri;
          int col = n0 + wc + nc * 16 + lr;
          size_t idx = (size_t)row * 768 + col;
          float rv = vres[idx];
          C[idx] = f2bf((1.0f - lm) * acc[mr][nc][ri] + lm * rv);
          out1[idx] = rv;
        }
    return;
  }

  // ---- Q/K path: RMS-norm + rotary, two 64-row groups via LDS ----
  const float EPS = 1.1920928955078125e-07f;
  const int frow = tid >> 2;       // 0..63 (row within group)
  const int q4 = tid & 3;          // col-quarter
#pragma unroll
  for (int grp = 0; grp < 2; grp++) {
    // stage: waves with (w>>1)==grp write their 64 rows
    if ((w >> 1) == grp) {
#pragma unroll
      for (int mr = 0; mr < 4; mr++)
#pragma unroll
        for (int nc = 0; nc < 4; nc++)
#pragma unroll
          for (int ri = 0; ri < 4; ri++)
            fs[mr * 16 + lg * 4 + ri][wc + nc * 16 + lr] = acc[mr][nc][ri];
    }
    __syncthreads();
    {
      const int grow = m0 + grp * 64 + frow;
      // sum of squares over this thread's 32 cols, reduce over 4-group
      float ss = 0.0f;
#pragma unroll
      for (int j = 0; j < 32; j++) {
        float v = fs[frow][q4 * 32 + j];
        ss += v * v;
      }
      ss += __shfl_xor(ss, 1);
      ss += __shfl_xor(ss, 2);
      float rn = rsqrtf(ss * (1.0f / 128.0f) + EPS);
      if (q4 < 2) {
        const int d0 = q4 * 32;
        const int tpos = pos[grow];
        u16 y1[32], y2[32];
        if (q4 == 0) {
#pragma unroll
          for (int j = 0; j < 32; j++) {
            float a = fs[frow][j] * rn;
            float b = fs[frow][64 + j] * rn;
            float afq = exp2f(-10.0f * (float)j * (1.0f / 31.0f));
            float th = (float)tpos * afq;
            float sn, c;
            sincosf(th, &sn, &c);
            y1[j] = f2bf(a * c + b * sn);
            y2[j] = f2bf(b * c - a * sn);
          }
        } else {
#pragma unroll
          for (int j = 0; j < 32; j++) {
            y1[j] = f2bf(fs[frow][32 + j] * rn);
            y2[j] = f2bf(fs[frow][96 + j] * rn);
          }
        }
        u16* cp = C + (size_t)grow * 768 + n0 + d0;
#pragma unroll
        for (int q = 0; q < 4; q++) {
          *(short8*)(cp + q * 8) = *(const short8*)(&y1[q * 8]);
          *(short8*)(cp + 64 + q * 8) = *(const short8*)(&y2[q * 8]);
        }
      }
    }
    __syncthreads();   // group done; LDS reusable
  }
}

// PROJ (r12-proven): A = accO/accL (fused finalize), output f32 to d_out.
__global__ __launch_bounds__(256) void r17_gemm_proj(const float* __restrict__ accO,
                                                     const float* __restrict__ accL,
                                                     const float* __restrict__ W,
                                                     float* __restrict__ C) {
  __shared__ u16 As[128 * 32];
  __shared__ u16 Bs[128 * 32];
  const int tid = threadIdx.x;
  const int w = tid >> 6, l = tid & 63;
  const int lr = l & 15, lg = l >> 4;
  const int m0 = blockIdx.x * 128, n0 = blockIdx.y * 128;
  const int wr = (w >> 1) * 64, wc = (w & 1) * 64;
  const int qrow = tid >> 1;
  const int qoff = (tid & 1) * 16;
  f32x4 acc[4][4] = {};
  for (int k0 = 0; k0 < 768; k0 += 32) {
    __syncthreads();
    {
      const float* ap = accO + (size_t)(m0 + qrow) * 768 + k0 + qoff;
      float rl = 1.0f / accL[(m0 + qrow) * 6 + (k0 >> 7)];
      u16* dp = As + qrow * 32 + qoff;
#pragma unroll
      for (int q = 0; q < 4; q++) {
        float4 f = ((const float4*)ap)[q];
        ushort4 b;
        b.x = f2bf(f.x * rl); b.y = f2bf(f.y * rl);
        b.z = f2bf(f.z * rl); b.w = f2bf(f.w * rl);
        *(ushort4*)(dp + q * 4) = b;
      }
      const float* wp = W + (size_t)(n0 + qrow) * 768 + k0 + qoff;
      u16* bp = Bs + qrow * 32 + qoff;
#pragma unroll
      for (int q = 0; q < 4; q++) {
        float4 f = ((const float4*)wp)[q];
        ushort4 b;
        b.x = f2bf(f.x); b.y = f2bf(f.y); b.z = f2bf(f.z); b.w = f2bf(f.w);
        *(ushort4*)(bp + q * 4) = b;
      }
    }
    __syncthreads();
    short8 af[4], bfr[4];
#pragma unroll
    for (int mr = 0; mr < 4; mr++) af[mr] = *(const short8*)(As + (wr + mr * 16 + lr) * 32 + lg * 8);
#pragma unroll
    for (int nc = 0; nc < 4; nc++) bfr[nc] = *(const short8*)(Bs + (wc + nc * 16 + lr) * 32 + lg * 8);
#pragma unroll
    for (int mr = 0; mr < 4; mr++)
#pragma unroll
      for (int nc = 0; nc < 4; nc++)
        acc[mr][nc] = __builtin_amdgcn_mfma_f32_16x16x32_bf16(af[mr], bfr[nc], acc[mr][nc], 0, 0, 0);
  }
#pragma unroll
  for (int mr = 0; mr < 4; mr++)
#pragma unroll
    for (int nc = 0; nc < 4; nc++)
#pragma unroll
      for (int ri = 0; ri < 4; ri++) {
        int row = m0 + wr + mr * 16 + lg * 4 + ri;
        int col = n0 + wc + nc * 16 + lr;
        C[(size_t)row * 768 + col] = acc[mr][nc][ri];
      }
}

// ---------------------------------------------------------------------------
// Kernel 4: causal flash attention (r12-exact config, 4x reproduced ~73 us).
// ---------------------------------------------------------------------------
__global__ __launch_bounds__(128, 2) void r17_attn(const u16* __restrict__ Q,
                                                   const u16* __restrict__ K,
                                                   const u16* __restrict__ V,
                                                   float* __restrict__ accO,
                                                   float* __restrict__ accL) {
  const int bx = blockIdx.x;          // 0..959
  const int h = bx / 160;
  const int u = 159 - (bx - h * 160);
  int qt, kc;
  if (u < 16)      { qt = u;                      kc = 0; }
  else if (u < 48) { int v = u - 16; qt = 16 + (v >> 1); kc = v & 1; }
  else if (u < 96) { int v = u - 48; int q3 = v / 3; qt = 32 + q3; kc = v - 3 * q3; }
  else             { int v = u - 96; qt = 48 + (v >> 2); kc = v & 3; }
  const int rowmax = 64 * qt + 63;
  const int c0 = kc << 10;
  const bool islast = (c0 + 1024 > rowmax);
  const int cend = islast ? (rowmax + 1) : (c0 + 1024);
  const int niter = (cend - c0) >> 6;

  const int tid = threadIdx.x;
  const int wv = tid >> 6, l = tid & 63;
  const int lq = l & 31;
  const int hi = l >> 5;

  __shared__ u16 Ks[64][128];
  __shared__ u16 vt[128][72];

  const int c_ = tid & 31, cc = c_ * 4, g = tid >> 5;
  const int vswz = (c_ & 7) << 3;

  const int qr = qt * 64 + wv * 32;
  const int qrow = qr + lq;

  short8 qf[8];
  {
    const u16* qp = Q + (size_t)qrow * 768 + h * 128 + hi * 8;
#pragma unroll
    for (int s = 0; s < 8; s++) qf[s] = *(const short8*)(qp + s * 16);
  }
  f32x16 oacc[4] = {};
  float lsum = 0.0f;

  for (int kv = 0; kv < niter; kv++) {
    const int k0 = c0 + kv * 64;

#pragma unroll
    for (int i = 0; i < 8; i++) {
      int rbase = wv * 32 + i * 4;
      int row = rbase + (l >> 4);
      int blk = (l & 15) ^ (row & 7);
      lds_ld16(K + (size_t)(k0 + row) * 768 + h * 128 + blk * 8, &Ks[rbase][0]);
    }
#pragma unroll
    for (int it = 0; it < 8; it++) {
      int rloc = 2 * (g + 4 * it);
      ushort4 va = *(const ushort4*)(V + (size_t)(k0 + rloc) * 768 + h * 128 + cc);
      ushort4 vb = *(const ushort4*)(V + (size_t)(k0 + rloc + 1) * 768 + h * 128 + cc);
      int rs = rloc ^ vswz;
      u16 a0[4] = {va.x, va.y, va.z, va.w};
      u16 b0[4] = {vb.x, vb.y, vb.z, vb.w};
#pragma unroll
      for (int q = 0; q < 4; q++) {
        ushort2 t2; t2.x = a0[q]; t2.y = b0[q];
        *(ushort2*)&vt[cc + q][rs] = t2;
      }
    }
    __syncthreads();

    f32x16 sac0 = {}, sac1 = {};
    __builtin_amdgcn_s_setprio(1);
    {
      const int r0_ = lq, r1_ = 32 + lq;
#pragma unroll
      for (int s = 0; s < 8; s++) {
        short8 kf0 = *(const short8*)(&Ks[r0_][((s * 2 + hi) ^ (r0_ & 7)) * 8]);
        sac0 = __builtin_amdgcn_mfma_f32_32x32x16_bf16(kf0, qf[s], sac0, 0, 0, 0);
      }
#pragma unroll
      for (int s = 0; s < 8; s++) {
        short8 kf1 = *(const short8*)(&Ks[r1_][((s * 2 + hi) ^ (r1_ & 7)) * 8]);
        sac1 = __builtin_amdgcn_mfma_f32_32x32x16_bf16(kf1, qf[s], sac1, 0, 0, 0);
      }
    }
    __builtin_amdgcn_s_setprio(0);

    float p[32];
    const bool maskit = islast && (kv == niter - 1);
    if (maskit) {
#pragma unroll
      for (int r = 0; r < 16; r++) {
        int kvg = k0 + (r & 3) + 8 * (r >> 2) + 4 * hi;
        p[r] = (kvg <= qrow) ? exp2f(sac0[r] * SCALE2) : 0.0f;
      }
#pragma unroll
      for (int r = 0; r < 16; r++) {
        int kvg = k0 + 32 + (r & 3) + 8 * (r >> 2) + 4 * hi;
        p[16 + r] = (kvg <= qrow) ? exp2f(sac1[r] * SCALE2) : 0.0f;
      }
    } else {
#pragma unroll
      for (int r = 0; r < 16; r++) p[r] = exp2f(sac0[r] * SCALE2);
#pragma unroll
      for (int r = 0; r < 16; r++) p[16 + r] = exp2f(sac1[r] * SCALE2);
    }
#pragma unroll
    for (int i = 0; i < 32; i++) lsum += p[i];

    union { unsigned int w[4]; short8 v; } pa[4];
#pragma unroll
    for (int s = 0; s < 4; s++) {
      const int b = s * 8;
      unsigned int cA0 = cvtpk_bf16(p[b + 0], p[b + 1]);
      unsigned int cA1 = cvtpk_bf16(p[b + 2], p[b + 3]);
      unsigned int cB0 = cvtpk_bf16(p[b + 4], p[b + 5]);
      unsigned int cB1 = cvtpk_bf16(p[b + 6], p[b + 7]);
      u32x2 s0 = __builtin_amdgcn_permlane32_swap(cA0, cB0, false, false);
      u32x2 s1 = __builtin_amdgcn_permlane32_swap(cA1, cB1, false, false);
      pa[s].w[0] = s0[0]; pa[s].w[1] = s1[0]; pa[s].w[2] = s0[1]; pa[s].w[3] = s1[1];
    }

    __builtin_amdgcn_s_setprio(1);
#pragma unroll
    for (int dt = 0; dt < 4; dt++) {
      const int d = dt * 32 + lq;
      const int dz = ((d >> 2) & 7) << 3;
#pragma unroll
      for (int s = 0; s < 4; s++) {
        short8 vf = *(const short8*)(&vt[d][(s * 16 + hi * 8) ^ dz]);
        oacc[dt] = __builtin_amdgcn_mfma_f32_32x32x16_bf16(pa[s].v, vf, oacc[dt], 0, 0, 0);
      }
    }
    __builtin_amdgcn_s_setprio(0);
    __syncthreads();
  }

#pragma unroll
  for (int dt = 0; dt < 4; dt++) {
    const int d = dt * 32 + lq;
#pragma unroll
    for (int r = 0; r < 16; r++) {
      int qrw = qr + (r & 3) + 8 * (r >> 2) + 4 * hi;
      unsafeAtomicAdd(&accO[(size_t)qrw * 768 + h * 128 + d], oacc[dt][r]);
    }
  }
  unsafeAtomicAdd(&accL[qrow * 6 + h], lsum);
}

// ---------------------------------------------------------------------------
// d_out FLOAT32: out0 = y@Wo^T [3145728 f32], out1 = v_residual [3145728].
// Workspace (r12 layout, 37.9 MB): xb@0, qb, kb, vb (u16), accO+accL (f32).
// ---------------------------------------------------------------------------
extern "C" void kernel_launch(void* const* d_in, const int* in_sizes, int n_in,
                              void* d_out, int out_size, void* d_ws, size_t ws_size,
                              hipStream_t stream) {
  const float* x = (const float*)d_in[0];
  const float* vres = (const float*)d_in[1];
  const float* Wq = (const float*)d_in[2];
  const float* Wk = (const float*)d_in[3];
  const float* Wv = (const float*)d_in[4];
  const float* Wo = (const float*)d_in[5];
  const float* lamb = (const float*)d_in[6];
  const int* pos = (const int*)d_in[7];
  float* out = (float*)d_out;

  u16* xb = (u16*)d_ws;
  u16* qb = xb + 3145728;
  u16* kb = qb + 3145728;
  u16* vb = kb + 3145728;
  float* accO = (float*)((char*)d_ws + 25165824);
  float* accL = accO + 3145728;
  float* out1 = out + 3145728;

  r17_cvt_x<<<6168, 256, 0, stream>>>(x, xb, accO);
  r17_gemm_qkv<<<dim3(32, 6, 3), 256, 0, stream>>>(xb, Wq, Wk, Wv, qb, kb, vb,
                                                   vres, lamb, pos, out1);
  r17_attn<<<960, 128, 0, stream>>>(qb, kb, vb, accO, accL);
  r17_gemm_proj<<<dim3(32, 6), 256, 0, stream>>>(accO, accL, Wo, out);
}

// Round 18
// 180.656 us; speedup vs baseline: 1.1971x; 1.1971x over previous
//
#include <hip/hip_runtime.h>
#include <hip/hip_bf16.h>

typedef unsigned short u16;
typedef __attribute__((ext_vector_type(8))) short short8;
typedef __attribute__((ext_vector_type(4))) float f32x4;
typedef __attribute__((ext_vector_type(16))) float f32x16;
typedef __attribute__((ext_vector_type(2))) unsigned int u32x2;

#define MODEL 768
// 1/sqrt(128) * log2(e): exp(s/sqrt(128)) == exp2(s * SCALE2)
#define SCALE2 0.1275174137f

__device__ __forceinline__ float bf2f(u16 u) {
  unsigned int x = ((unsigned int)u) << 16;
  return __uint_as_float(x);
}
__device__ __forceinline__ u16 f2bf(float f) {
  unsigned int x = __float_as_uint(f);
  unsigned int r = (x + 0x7FFFu + ((x >> 16) & 1u)) >> 16;
  return (u16)r;
}
__device__ __forceinline__ void lds_ld16(const u16* g, u16* l) {
  __builtin_amdgcn_global_load_lds((const __attribute__((address_space(1))) void*)g,
                                   (__attribute__((address_space(3))) void*)l, 16, 0, 0);
}
__device__ __forceinline__ unsigned int cvtpk_bf16(float lo, float hi_) {
  unsigned int r;
  asm("v_cvt_pk_bf16_f32 %0, %1, %2" : "=v"(r) : "v"(lo), "v"(hi_));
  return r;
}

// ---------------------------------------------------------------------------
// Kernel 1: x f32 -> bf16 (786432 float4 units) AND zero accO/accL.
// ---------------------------------------------------------------------------
__global__ __launch_bounds__(256) void r18_cvt_x(const float* __restrict__ x,
                                                 u16* __restrict__ xb,
                                                 float* __restrict__ accZ) {
  int i = blockIdx.x * 256 + threadIdx.x;
  if (i < 786432) {
    float4 v = ((const float4*)x)[i];
    ushort4 o;
    o.x = f2bf(v.x); o.y = f2bf(v.y); o.z = f2bf(v.z); o.w = f2bf(v.w);
    ((ushort4*)xb)[i] = o;
  } else if (i < 786432 + 792576) {
    float4 z = {0.0f, 0.0f, 0.0f, 0.0f};
    ((float4*)accZ)[i - 786432] = z;
  }
}

// ---------------------------------------------------------------------------
// GEMM QKV (r16 main loop).  Epilogue: bz<2 -> plain bf16 write (normrope
// kernel handles Q/K norm+rotary); bz=2 -> REGISTER-ONLY fused lambda-mix
// with vres + out1 = vres passthrough (no LDS, no trig, no local arrays).
// ---------------------------------------------------------------------------
__global__ __launch_bounds__(256) void r18_gemm_qkv(const u16* __restrict__ A,
                                                    const float* __restrict__ W0,
                                                    const float* __restrict__ W1,
                                                    const float* __restrict__ W2,
                                                    u16* __restrict__ C0,
                                                    u16* __restrict__ C1,
                                                    u16* __restrict__ C2,
                                                    const float* __restrict__ vres,
                                                    const float* __restrict__ lambp,
                                                    float* __restrict__ out1) {
  const int bz = blockIdx.z;
  const float* W = (bz == 0) ? W0 : (bz == 1) ? W1 : W2;
  u16* C = (bz == 0) ? C0 : (bz == 1) ? C1 : C2;
  __shared__ u16 As[128 * 32];
  __shared__ u16 Bs[128 * 32];
  const int tid = threadIdx.x;
  const int w = tid >> 6, l = tid & 63;
  const int lr = l & 15, lg = l >> 4;
  const int m0 = blockIdx.x * 128, n0 = blockIdx.y * 128;
  const int wr = (w >> 1) * 64, wc = (w & 1) * 64;
  const int sr = w * 32 + (l >> 2);
  const int sc = (l & 3) * 8;
  const int qrow = tid >> 1;
  const int qoff = (tid & 1) * 16;
  f32x4 acc[4][4] = {};
  for (int k0 = 0; k0 < 768; k0 += 32) {
    __syncthreads();
    lds_ld16(A + (size_t)(m0 + sr) * 768 + k0 + sc, As + (w * 2 + 0) * 512);
    lds_ld16(A + (size_t)(m0 + sr + 16) * 768 + k0 + sc, As + (w * 2 + 1) * 512);
    {
      const float* wp = W + (size_t)(n0 + qrow) * 768 + k0 + qoff;
      u16* bp = Bs + qrow * 32 + qoff;
#pragma unroll
      for (int q = 0; q < 4; q++) {
        float4 f = ((const float4*)wp)[q];
        ushort4 b;
        b.x = f2bf(f.x); b.y = f2bf(f.y); b.z = f2bf(f.z); b.w = f2bf(f.w);
        *(ushort4*)(bp + q * 4) = b;
      }
    }
    __syncthreads();
    short8 af[4], bfr[4];
#pragma unroll
    for (int mr = 0; mr < 4; mr++) af[mr] = *(const short8*)(As + (wr + mr * 16 + lr) * 32 + lg * 8);
#pragma unroll
    for (int nc = 0; nc < 4; nc++) bfr[nc] = *(const short8*)(Bs + (wc + nc * 16 + lr) * 32 + lg * 8);
#pragma unroll
    for (int mr = 0; mr < 4; mr++)
#pragma unroll
      for (int nc = 0; nc < 4; nc++)
        acc[mr][nc] = __builtin_amdgcn_mfma_f32_16x16x32_bf16(af[mr], bfr[nc], acc[mr][nc], 0, 0, 0);
  }
  if (bz == 2) {
    const float lm = *lambp;
#pragma unroll
    for (int mr = 0; mr < 4; mr++)
#pragma unroll
      for (int nc = 0; nc < 4; nc++)
#pragma unroll
        for (int ri = 0; ri < 4; ri++) {
          int row = m0 + wr + mr * 16 + lg * 4 + ri;
          int col = n0 + wc + nc * 16 + lr;
          size_t idx = (size_t)row * 768 + col;
          float rv = vres[idx];
          C[idx] = f2bf((1.0f - lm) * acc[mr][nc][ri] + lm * rv);
          out1[idx] = rv;
        }
  } else {
#pragma unroll
    for (int mr = 0; mr < 4; mr++)
#pragma unroll
      for (int nc = 0; nc < 4; nc++)
#pragma unroll
        for (int ri = 0; ri < 4; ri++) {
          int row = m0 + wr + mr * 16 + lg * 4 + ri;
          int col = n0 + wc + nc * 16 + lr;
          C[(size_t)row * 768 + col] = f2bf(acc[mr][nc][ri]);
        }
  }
}

// PROJ (r12-proven): A = accO/accL (fused finalize), output f32 to d_out.
__global__ __launch_bounds__(256) void r18_gemm_proj(const float* __restrict__ accO,
                                                     const float* __restrict__ accL,
                                                     const float* __restrict__ W,
                                                     float* __restrict__ C) {
  __shared__ u16 As[128 * 32];
  __shared__ u16 Bs[128 * 32];
  const int tid = threadIdx.x;
  const int w = tid >> 6, l = tid & 63;
  const int lr = l & 15, lg = l >> 4;
  const int m0 = blockIdx.x * 128, n0 = blockIdx.y * 128;
  const int wr = (w >> 1) * 64, wc = (w & 1) * 64;
  const int qrow = tid >> 1;
  const int qoff = (tid & 1) * 16;
  f32x4 acc[4][4] = {};
  for (int k0 = 0; k0 < 768; k0 += 32) {
    __syncthreads();
    {
      const float* ap = accO + (size_t)(m0 + qrow) * 768 + k0 + qoff;
      float rl = 1.0f / accL[(m0 + qrow) * 6 + (k0 >> 7)];
      u16* dp = As + qrow * 32 + qoff;
#pragma unroll
      for (int q = 0; q < 4; q++) {
        float4 f = ((const float4*)ap)[q];
        ushort4 b;
        b.x = f2bf(f.x * rl); b.y = f2bf(f.y * rl);
        b.z = f2bf(f.z * rl); b.w = f2bf(f.w * rl);
        *(ushort4*)(dp + q * 4) = b;
      }
      const float* wp = W + (size_t)(n0 + qrow) * 768 + k0 + qoff;
      u16* bp = Bs + qrow * 32 + qoff;
#pragma unroll
      for (int q = 0; q < 4; q++) {
        float4 f = ((const float4*)wp)[q];
        ushort4 b;
        b.x = f2bf(f.x); b.y = f2bf(f.y); b.z = f2bf(f.z); b.w = f2bf(f.w);
        *(ushort4*)(bp + q * 4) = b;
      }
    }
    __syncthreads();
    short8 af[4], bfr[4];
#pragma unroll
    for (int mr = 0; mr < 4; mr++) af[mr] = *(const short8*)(As + (wr + mr * 16 + lr) * 32 + lg * 8);
#pragma unroll
    for (int nc = 0; nc < 4; nc++) bfr[nc] = *(const short8*)(Bs + (wc + nc * 16 + lr) * 32 + lg * 8);
#pragma unroll
    for (int mr = 0; mr < 4; mr++)
#pragma unroll
      for (int nc = 0; nc < 4; nc++)
        acc[mr][nc] = __builtin_amdgcn_mfma_f32_16x16x32_bf16(af[mr], bfr[nc], acc[mr][nc], 0, 0, 0);
  }
#pragma unroll
  for (int mr = 0; mr < 4; mr++)
#pragma unroll
    for (int nc = 0; nc < 4; nc++)
#pragma unroll
      for (int ri = 0; ri < 4; ri++) {
        int row = m0 + wr + mr * 16 + lg * 4 + ri;
        int col = n0 + wc + nc * 16 + lr;
        C[(size_t)row * 768 + col] = acc[mr][nc][ri];
      }
}

// ---------------------------------------------------------------------------
// Kernel 3: fused RMS-norm + rotary for Q,K ONLY (V handled in gemm_qkv).
// One wave per (t, head) row; lane handles dims (l, l+64) = rotary pair.
// ---------------------------------------------------------------------------
__global__ __launch_bounds__(256) void r18_normrope(u16* __restrict__ qb,
                                                    u16* __restrict__ kb,
                                                    const int* __restrict__ pos) {
  const int wg = blockIdx.x * 4 + (threadIdx.x >> 6);
  const int l = threadIdx.x & 63;
  const int t = wg / 6;
  const int h = wg - t * 6;
  const size_t base = (size_t)t * MODEL + h * 128;
  const float EPS = 1.1920928955078125e-07f;

  float c = 1.0f, sn = 0.0f;
  if (l < 32) {
    float af = exp2f(-10.0f * (float)l * (1.0f / 31.0f));
    float th = (float)pos[t] * af;
    sincosf(th, &sn, &c);
  }
  {
    float a = bf2f(qb[base + l]), b = bf2f(qb[base + 64 + l]);
    float ss = a * a + b * b;
#pragma unroll
    for (int off = 32; off; off >>= 1) ss += __shfl_xor(ss, off);
    float r = rsqrtf(ss * (1.0f / 128.0f) + EPS);
    float an = a * r, bn = b * r;
    qb[base + l] = f2bf(an * c + bn * sn);
    qb[base + 64 + l] = f2bf(bn * c - an * sn);
  }
  {
    float a = bf2f(kb[base + l]), b = bf2f(kb[base + 64 + l]);
    float ss = a * a + b * b;
#pragma unroll
    for (int off = 32; off; off >>= 1) ss += __shfl_xor(ss, off);
    float r = rsqrtf(ss * (1.0f / 128.0f) + EPS);
    float an = a * r, bn = b * r;
    kb[base + l] = f2bf(an * c + bn * sn);
    kb[base + 64 + l] = f2bf(bn * c - an * sn);
  }
}

// ---------------------------------------------------------------------------
// Kernel 4: causal flash attention (r12-exact config, 4x reproduced ~73 us):
// SPLIT-KV chunk 1024, 2-wave blocks x 32 q-rows, 960 blocks longest-first,
// 32x32 MFMA swapped QK^T, in-register P via cvt_pk + permlane32_swap,
// static-max softmax, f32 hardware atomics.  LDS 34KB -> 4 blocks/CU.
// ---------------------------------------------------------------------------
__global__ __launch_bounds__(128, 2) void r18_attn(const u16* __restrict__ Q,
                                                   const u16* __restrict__ K,
                                                   const u16* __restrict__ V,
                                                   float* __restrict__ accO,
                                                   float* __restrict__ accL) {
  const int bx = blockIdx.x;          // 0..959
  const int h = bx / 160;
  const int u = 159 - (bx - h * 160);
  int qt, kc;
  if (u < 16)      { qt = u;                      kc = 0; }
  else if (u < 48) { int v = u - 16; qt = 16 + (v >> 1); kc = v & 1; }
  else if (u < 96) { int v = u - 48; int q3 = v / 3; qt = 32 + q3; kc = v - 3 * q3; }
  else             { int v = u - 96; qt = 48 + (v >> 2); kc = v & 3; }
  const int rowmax = 64 * qt + 63;
  const int c0 = kc << 10;
  const bool islast = (c0 + 1024 > rowmax);
  const int cend = islast ? (rowmax + 1) : (c0 + 1024);
  const int niter = (cend - c0) >> 6;

  const int tid = threadIdx.x;
  const int wv = tid >> 6, l = tid & 63;
  const int lq = l & 31;
  const int hi = l >> 5;

  __shared__ u16 Ks[64][128];
  __shared__ u16 vt[128][72];

  const int c_ = tid & 31, cc = c_ * 4, g = tid >> 5;
  const int vswz = (c_ & 7) << 3;

  const int qr = qt * 64 + wv * 32;
  const int qrow = qr + lq;

  short8 qf[8];
  {
    const u16* qp = Q + (size_t)qrow * 768 + h * 128 + hi * 8;
#pragma unroll
    for (int s = 0; s < 8; s++) qf[s] = *(const short8*)(qp + s * 16);
  }
  f32x16 oacc[4] = {};
  float lsum = 0.0f;

  for (int kv = 0; kv < niter; kv++) {
    const int k0 = c0 + kv * 64;

#pragma unroll
    for (int i = 0; i < 8; i++) {
      int rbase = wv * 32 + i * 4;
      int row = rbase + (l >> 4);
      int blk = (l & 15) ^ (row & 7);
      lds_ld16(K + (size_t)(k0 + row) * 768 + h * 128 + blk * 8, &Ks[rbase][0]);
    }
#pragma unroll
    for (int it = 0; it < 8; it++) {
      int rloc = 2 * (g + 4 * it);
      ushort4 va = *(const ushort4*)(V + (size_t)(k0 + rloc) * 768 + h * 128 + cc);
      ushort4 vb = *(const ushort4*)(V + (size_t)(k0 + rloc + 1) * 768 + h * 128 + cc);
      int rs = rloc ^ vswz;
      u16 a0[4] = {va.x, va.y, va.z, va.w};
      u16 b0[4] = {vb.x, vb.y, vb.z, vb.w};
#pragma unroll
      for (int q = 0; q < 4; q++) {
        ushort2 t2; t2.x = a0[q]; t2.y = b0[q];
        *(ushort2*)&vt[cc + q][rs] = t2;
      }
    }
    __syncthreads();

    f32x16 sac0 = {}, sac1 = {};
    __builtin_amdgcn_s_setprio(1);
    {
      const int r0_ = lq, r1_ = 32 + lq;
#pragma unroll
      for (int s = 0; s < 8; s++) {
        short8 kf0 = *(const short8*)(&Ks[r0_][((s * 2 + hi) ^ (r0_ & 7)) * 8]);
        sac0 = __builtin_amdgcn_mfma_f32_32x32x16_bf16(kf0, qf[s], sac0, 0, 0, 0);
      }
#pragma unroll
      for (int s = 0; s < 8; s++) {
        short8 kf1 = *(const short8*)(&Ks[r1_][((s * 2 + hi) ^ (r1_ & 7)) * 8]);
        sac1 = __builtin_amdgcn_mfma_f32_32x32x16_bf16(kf1, qf[s], sac1, 0, 0, 0);
      }
    }
    __builtin_amdgcn_s_setprio(0);

    float p[32];
    const bool maskit = islast && (kv == niter - 1);
    if (maskit) {
#pragma unroll
      for (int r = 0; r < 16; r++) {
        int kvg = k0 + (r & 3) + 8 * (r >> 2) + 4 * hi;
        p[r] = (kvg <= qrow) ? exp2f(sac0[r] * SCALE2) : 0.0f;
      }
#pragma unroll
      for (int r = 0; r < 16; r++) {
        int kvg = k0 + 32 + (r & 3) + 8 * (r >> 2) + 4 * hi;
        p[16 + r] = (kvg <= qrow) ? exp2f(sac1[r] * SCALE2) : 0.0f;
      }
    } else {
#pragma unroll
      for (int r = 0; r < 16; r++) p[r] = exp2f(sac0[r] * SCALE2);
#pragma unroll
      for (int r = 0; r < 16; r++) p[16 + r] = exp2f(sac1[r] * SCALE2);
    }
#pragma unroll
    for (int i = 0; i < 32; i++) lsum += p[i];

    union { unsigned int w[4]; short8 v; } pa[4];
#pragma unroll
    for (int s = 0; s < 4; s++) {
      const int b = s * 8;
      unsigned int cA0 = cvtpk_bf16(p[b + 0], p[b + 1]);
      unsigned int cA1 = cvtpk_bf16(p[b + 2], p[b + 3]);
      unsigned int cB0 = cvtpk_bf16(p[b + 4], p[b + 5]);
      unsigned int cB1 = cvtpk_bf16(p[b + 6], p[b + 7]);
      u32x2 s0 = __builtin_amdgcn_permlane32_swap(cA0, cB0, false, false);
      u32x2 s1 = __builtin_amdgcn_permlane32_swap(cA1, cB1, false, false);
      pa[s].w[0] = s0[0]; pa[s].w[1] = s1[0]; pa[s].w[2] = s0[1]; pa[s].w[3] = s1[1];
    }

    __builtin_amdgcn_s_setprio(1);
#pragma unroll
    for (int dt = 0; dt < 4; dt++) {
      const int d = dt * 32 + lq;
      const int dz = ((d >> 2) & 7) << 3;
#pragma unroll
      for (int s = 0; s < 4; s++) {
        short8 vf = *(const short8*)(&vt[d][(s * 16 + hi * 8) ^ dz]);
        oacc[dt] = __builtin_amdgcn_mfma_f32_32x32x16_bf16(pa[s].v, vf, oacc[dt], 0, 0, 0);
      }
    }
    __builtin_amdgcn_s_setprio(0);
    __syncthreads();
  }

#pragma unroll
  for (int dt = 0; dt < 4; dt++) {
    const int d = dt * 32 + lq;
#pragma unroll
    for (int r = 0; r < 16; r++) {
      int qrw = qr + (r & 3) + 8 * (r >> 2) + 4 * hi;
      unsafeAtomicAdd(&accO[(size_t)qrw * 768 + h * 128 + d], oacc[dt][r]);
    }
  }
  unsafeAtomicAdd(&accL[qrow * 6 + h], lsum);
}

// ---------------------------------------------------------------------------
// d_out FLOAT32: out0 = y@Wo^T [3145728 f32], out1 = v_residual [3145728].
// Workspace (r12 layout, 37.9 MB): xb@0, qb, kb, vb (u16), accO+accL (f32).
// ---------------------------------------------------------------------------
extern "C" void kernel_launch(void* const* d_in, const int* in_sizes, int n_in,
                              void* d_out, int out_size, void* d_ws, size_t ws_size,
                              hipStream_t stream) {
  const float* x = (const float*)d_in[0];
  const float* vres = (const float*)d_in[1];
  const float* Wq = (const float*)d_in[2];
  const float* Wk = (const float*)d_in[3];
  const float* Wv = (const float*)d_in[4];
  const float* Wo = (const float*)d_in[5];
  const float* lamb = (const float*)d_in[6];
  const int* pos = (const int*)d_in[7];
  float* out = (float*)d_out;

  u16* xb = (u16*)d_ws;
  u16* qb = xb + 3145728;
  u16* kb = qb + 3145728;
  u16* vb = kb + 3145728;
  float* accO = (float*)((char*)d_ws + 25165824);
  float* accL = accO + 3145728;
  float* out1 = out + 3145728;

  r18_cvt_x<<<6168, 256, 0, stream>>>(x, xb, accO);
  r18_gemm_qkv<<<dim3(32, 6, 3), 256, 0, stream>>>(xb, Wq, Wk, Wv, qb, kb, vb,
                                                   vres, lamb, out1);
  r18_normrope<<<6144, 256, 0, stream>>>(qb, kb, pos);
  r18_attn<<<960, 128, 0, stream>>>(qb, kb, vb, accO, accL);
  r18_gemm_proj<<<dim3(32, 6), 256, 0, stream>>>(accO, accL, Wo, out);
}

// Round 19
// 159.726 us; speedup vs baseline: 1.3540x; 1.1310x over previous
//
#include <hip/hip_runtime.h>
#include <hip/hip_bf16.h>

typedef unsigned short u16;
typedef __attribute__((ext_vector_type(8))) short short8;
typedef __attribute__((ext_vector_type(4))) float f32x4;
typedef __attribute__((ext_vector_type(16))) float f32x16;
typedef __attribute__((ext_vector_type(2))) unsigned int u32x2;

#define MODEL 768
// 1/sqrt(128) * log2(e): exp(s/sqrt(128)) == exp2(s * SCALE2)
#define SCALE2 0.1275174137f

__device__ __forceinline__ float bf2f(u16 u) {
  unsigned int x = ((unsigned int)u) << 16;
  return __uint_as_float(x);
}
__device__ __forceinline__ u16 f2bf(float f) {
  unsigned int x = __float_as_uint(f);
  unsigned int r = (x + 0x7FFFu + ((x >> 16) & 1u)) >> 16;
  return (u16)r;
}
__device__ __forceinline__ void lds_ld16(const u16* g, u16* l) {
  __builtin_amdgcn_global_load_lds((const __attribute__((address_space(1))) void*)g,
                                   (__attribute__((address_space(3))) void*)l, 16, 0, 0);
}
__device__ __forceinline__ unsigned int cvtpk_bf16(float lo, float hi_) {
  unsigned int r;
  asm("v_cvt_pk_bf16_f32 %0, %1, %2" : "=v"(r) : "v"(lo), "v"(hi_));
  return r;
}

// ---------------------------------------------------------------------------
// Kernel 1: x f32 -> bf16 (786432 float4 units) AND zero accO/accL.
// ---------------------------------------------------------------------------
__global__ __launch_bounds__(256) void r19_cvt_x(const float* __restrict__ x,
                                                 u16* __restrict__ xb,
                                                 float* __restrict__ accZ) {
  int i = blockIdx.x * 256 + threadIdx.x;
  if (i < 786432) {
    float4 v = ((const float4*)x)[i];
    ushort4 o;
    o.x = f2bf(v.x); o.y = f2bf(v.y); o.z = f2bf(v.z); o.w = f2bf(v.w);
    ((ushort4*)xb)[i] = o;
  } else if (i < 786432 + 792576) {
    float4 z = {0.0f, 0.0f, 0.0f, 0.0f};
    ((float4*)accZ)[i - 786432] = z;
  }
}

// ---------------------------------------------------------------------------
// GEMM QKV, 64-ROW TILES: C = A_bf16 * W_f32^T.  Tile 64x128, BK=32,
// 4 waves (2x2: each 32x64 via 2x4 16x16x32 frags).  Grid (64,6,3) = 1152
// blocks (~4.5/CU) -- 2x the TLP of the 128-row version on this
// latency-bound loop.  A via gload_lds (1 issue/wave); W f32->bf16 in
// staging (identical B-panel to r16).
// ---------------------------------------------------------------------------
__global__ __launch_bounds__(256) void r19_gemm_qkv(const u16* __restrict__ A,
                                                    const float* __restrict__ W0,
                                                    const float* __restrict__ W1,
                                                    const float* __restrict__ W2,
                                                    u16* __restrict__ C0,
                                                    u16* __restrict__ C1,
                                                    u16* __restrict__ C2) {
  const float* W = (blockIdx.z == 0) ? W0 : (blockIdx.z == 1) ? W1 : W2;
  u16* C = (blockIdx.z == 0) ? C0 : (blockIdx.z == 1) ? C1 : C2;
  __shared__ u16 As[64 * 32];
  __shared__ u16 Bs[128 * 32];
  const int tid = threadIdx.x;
  const int w = tid >> 6, l = tid & 63;
  const int lr = l & 15, lg = l >> 4;
  const int m0 = blockIdx.x * 64, n0 = blockIdx.y * 128;
  const int wr = (w >> 1) * 32, wc = (w & 1) * 64;
  const int sr = w * 16 + (l >> 2);   // A staging row (1 issue/wave)
  const int sc = (l & 3) * 8;
  const int qrow = tid >> 1;          // B staging row 0..127
  const int qoff = (tid & 1) * 16;
  f32x4 acc[2][4] = {};
  for (int k0 = 0; k0 < 768; k0 += 32) {
    __syncthreads();
    lds_ld16(A + (size_t)(m0 + sr) * 768 + k0 + sc, As + w * 512);
    {
      const float* wp = W + (size_t)(n0 + qrow) * 768 + k0 + qoff;
      u16* bp = Bs + qrow * 32 + qoff;
#pragma unroll
      for (int q = 0; q < 4; q++) {
        float4 f = ((const float4*)wp)[q];
        ushort4 b;
        b.x = f2bf(f.x); b.y = f2bf(f.y); b.z = f2bf(f.z); b.w = f2bf(f.w);
        *(ushort4*)(bp + q * 4) = b;
      }
    }
    __syncthreads();
    short8 af[2], bfr[4];
#pragma unroll
    for (int mr = 0; mr < 2; mr++) af[mr] = *(const short8*)(As + (wr + mr * 16 + lr) * 32 + lg * 8);
#pragma unroll
    for (int nc = 0; nc < 4; nc++) bfr[nc] = *(const short8*)(Bs + (wc + nc * 16 + lr) * 32 + lg * 8);
#pragma unroll
    for (int mr = 0; mr < 2; mr++)
#pragma unroll
      for (int nc = 0; nc < 4; nc++)
        acc[mr][nc] = __builtin_amdgcn_mfma_f32_16x16x32_bf16(af[mr], bfr[nc], acc[mr][nc], 0, 0, 0);
  }
#pragma unroll
  for (int mr = 0; mr < 2; mr++)
#pragma unroll
    for (int nc = 0; nc < 4; nc++)
#pragma unroll
      for (int ri = 0; ri < 4; ri++) {
        int row = m0 + wr + mr * 16 + lg * 4 + ri;
        int col = n0 + wc + nc * 16 + lr;
        C[(size_t)row * 768 + col] = f2bf(acc[mr][nc][ri]);
      }
}

// ---------------------------------------------------------------------------
// GEMM PROJ, 64-ROW TILES: A = accO/accL (fused finalize), f32 out.
// Grid (64,6) = 384 blocks (vs 192 -- old grid didn't cover 256 CUs).
// ---------------------------------------------------------------------------
__global__ __launch_bounds__(256) void r19_gemm_proj(const float* __restrict__ accO,
                                                     const float* __restrict__ accL,
                                                     const float* __restrict__ W,
                                                     float* __restrict__ C) {
  __shared__ u16 As[64 * 32];
  __shared__ u16 Bs[128 * 32];
  const int tid = threadIdx.x;
  const int w = tid >> 6, l = tid & 63;
  const int lr = l & 15, lg = l >> 4;
  const int m0 = blockIdx.x * 64, n0 = blockIdx.y * 128;
  const int wr = (w >> 1) * 32, wc = (w & 1) * 64;
  const int arow = tid >> 2;          // A staging row 0..63
  const int aoff = (tid & 3) * 8;     // 8 floats per thread
  const int qrow = tid >> 1;          // B staging row 0..127
  const int qoff = (tid & 1) * 16;
  f32x4 acc[2][4] = {};
  for (int k0 = 0; k0 < 768; k0 += 32) {
    __syncthreads();
    {
      const float* ap = accO + (size_t)(m0 + arow) * 768 + k0 + aoff;
      float rl = 1.0f / accL[(m0 + arow) * 6 + (k0 >> 7)];
      u16* dp = As + arow * 32 + aoff;
      float4 f0 = ((const float4*)ap)[0];
      float4 f1 = ((const float4*)ap)[1];
      ushort4 b0, b1;
      b0.x = f2bf(f0.x * rl); b0.y = f2bf(f0.y * rl);
      b0.z = f2bf(f0.z * rl); b0.w = f2bf(f0.w * rl);
      b1.x = f2bf(f1.x * rl); b1.y = f2bf(f1.y * rl);
      b1.z = f2bf(f1.z * rl); b1.w = f2bf(f1.w * rl);
      *(ushort4*)(dp) = b0;
      *(ushort4*)(dp + 4) = b1;
      const float* wp = W + (size_t)(n0 + qrow) * 768 + k0 + qoff;
      u16* bp = Bs + qrow * 32 + qoff;
#pragma unroll
      for (int q = 0; q < 4; q++) {
        float4 f = ((const float4*)wp)[q];
        ushort4 b;
        b.x = f2bf(f.x); b.y = f2bf(f.y); b.z = f2bf(f.z); b.w = f2bf(f.w);
        *(ushort4*)(bp + q * 4) = b;
      }
    }
    __syncthreads();
    short8 af[2], bfr[4];
#pragma unroll
    for (int mr = 0; mr < 2; mr++) af[mr] = *(const short8*)(As + (wr + mr * 16 + lr) * 32 + lg * 8);
#pragma unroll
    for (int nc = 0; nc < 4; nc++) bfr[nc] = *(const short8*)(Bs + (wc + nc * 16 + lr) * 32 + lg * 8);
#pragma unroll
    for (int mr = 0; mr < 2; mr++)
#pragma unroll
      for (int nc = 0; nc < 4; nc++)
        acc[mr][nc] = __builtin_amdgcn_mfma_f32_16x16x32_bf16(af[mr], bfr[nc], acc[mr][nc], 0, 0, 0);
  }
#pragma unroll
  for (int mr = 0; mr < 2; mr++)
#pragma unroll
    for (int nc = 0; nc < 4; nc++)
#pragma unroll
      for (int ri = 0; ri < 4; ri++) {
        int row = m0 + wr + mr * 16 + lg * 4 + ri;
        int col = n0 + wc + nc * 16 + lr;
        C[(size_t)row * 768 + col] = acc[mr][nc][ri];
      }
}

// ---------------------------------------------------------------------------
// Kernel 3 (r16-exact): fused RMS-norm + rotary (Q,K) + lambda-mix (V)
// + out1 copy.
// ---------------------------------------------------------------------------
__global__ __launch_bounds__(256) void r19_normrope(u16* __restrict__ qb,
                                                    u16* __restrict__ kb,
                                                    u16* __restrict__ vb,
                                                    const float* __restrict__ vres,
                                                    const float* __restrict__ lambp,
                                                    const int* __restrict__ pos,
                                                    float* __restrict__ out1) {
  const int wg = blockIdx.x * 4 + (threadIdx.x >> 6);
  const int l = threadIdx.x & 63;
  const int t = wg / 6;
  const int h = wg - t * 6;
  const size_t base = (size_t)t * MODEL + h * 128;
  const float EPS = 1.1920928955078125e-07f;

  float c = 1.0f, sn = 0.0f;
  if (l < 32) {
    float af = exp2f(-10.0f * (float)l * (1.0f / 31.0f));
    float th = (float)pos[t] * af;
    sincosf(th, &sn, &c);
  }
  {
    float a = bf2f(qb[base + l]), b = bf2f(qb[base + 64 + l]);
    float ss = a * a + b * b;
#pragma unroll
    for (int off = 32; off; off >>= 1) ss += __shfl_xor(ss, off);
    float r = rsqrtf(ss * (1.0f / 128.0f) + EPS);
    float an = a * r, bn = b * r;
    qb[base + l] = f2bf(an * c + bn * sn);
    qb[base + 64 + l] = f2bf(bn * c - an * sn);
  }
  {
    float a = bf2f(kb[base + l]), b = bf2f(kb[base + 64 + l]);
    float ss = a * a + b * b;
#pragma unroll
    for (int off = 32; off; off >>= 1) ss += __shfl_xor(ss, off);
    float r = rsqrtf(ss * (1.0f / 128.0f) + EPS);
    float an = a * r, bn = b * r;
    kb[base + l] = f2bf(an * c + bn * sn);
    kb[base + 64 + l] = f2bf(bn * c - an * sn);
  }
  {
    float lm = *lambp;
    float a = bf2f(vb[base + l]), b = bf2f(vb[base + 64 + l]);
    float ra = vres[base + l], rb = vres[base + 64 + l];
    vb[base + l] = f2bf((1.0f - lm) * a + lm * ra);
    vb[base + 64 + l] = f2bf((1.0f - lm) * b + lm * rb);
    out1[base + l] = ra;
    out1[base + 64 + l] = rb;
  }
}

// ---------------------------------------------------------------------------
// Kernel 4 (r12-exact, 5x reproduced ~73 us): causal flash attention,
// SPLIT-KV chunk 1024, 2-wave x 32 q-rows, 960 blocks longest-first,
// 32x32 MFMA swapped QK^T, in-register P, static-max softmax, f32 atomics.
// ---------------------------------------------------------------------------
__global__ __launch_bounds__(128, 2) void r19_attn(const u16* __restrict__ Q,
                                                   const u16* __restrict__ K,
                                                   const u16* __restrict__ V,
                                                   float* __restrict__ accO,
                                                   float* __restrict__ accL) {
  const int bx = blockIdx.x;          // 0..959
  const int h = bx / 160;
  const int u = 159 - (bx - h * 160);
  int qt, kc;
  if (u < 16)      { qt = u;                      kc = 0; }
  else if (u < 48) { int v = u - 16; qt = 16 + (v >> 1); kc = v & 1; }
  else if (u < 96) { int v = u - 48; int q3 = v / 3; qt = 32 + q3; kc = v - 3 * q3; }
  else             { int v = u - 96; qt = 48 + (v >> 2); kc = v & 3; }
  const int rowmax = 64 * qt + 63;
  const int c0 = kc << 10;
  const bool islast = (c0 + 1024 > rowmax);
  const int cend = islast ? (rowmax + 1) : (c0 + 1024);
  const int niter = (cend - c0) >> 6;

  const int tid = threadIdx.x;
  const int wv = tid >> 6, l = tid & 63;
  const int lq = l & 31;
  const int hi = l >> 5;

  __shared__ u16 Ks[64][128];
  __shared__ u16 vt[128][72];

  const int c_ = tid & 31, cc = c_ * 4, g = tid >> 5;
  const int vswz = (c_ & 7) << 3;

  const int qr = qt * 64 + wv * 32;
  const int qrow = qr + lq;

  short8 qf[8];
  {
    const u16* qp = Q + (size_t)qrow * 768 + h * 128 + hi * 8;
#pragma unroll
    for (int s = 0; s < 8; s++) qf[s] = *(const short8*)(qp + s * 16);
  }
  f32x16 oacc[4] = {};
  float lsum = 0.0f;

  for (int kv = 0; kv < niter; kv++) {
    const int k0 = c0 + kv * 64;

#pragma unroll
    for (int i = 0; i < 8; i++) {
      int rbase = wv * 32 + i * 4;
      int row = rbase + (l >> 4);
      int blk = (l & 15) ^ (row & 7);
      lds_ld16(K + (size_t)(k0 + row) * 768 + h * 128 + blk * 8, &Ks[rbase][0]);
    }
#pragma unroll
    for (int it = 0; it < 8; it++) {
      int rloc = 2 * (g + 4 * it);
      ushort4 va = *(const ushort4*)(V + (size_t)(k0 + rloc) * 768 + h * 128 + cc);
      ushort4 vb = *(const ushort4*)(V + (size_t)(k0 + rloc + 1) * 768 + h * 128 + cc);
      int rs = rloc ^ vswz;
      u16 a0[4] = {va.x, va.y, va.z, va.w};
      u16 b0[4] = {vb.x, vb.y, vb.z, vb.w};
#pragma unroll
      for (int q = 0; q < 4; q++) {
        ushort2 t2; t2.x = a0[q]; t2.y = b0[q];
        *(ushort2*)&vt[cc + q][rs] = t2;
      }
    }
    __syncthreads();

    f32x16 sac0 = {}, sac1 = {};
    __builtin_amdgcn_s_setprio(1);
    {
      const int r0_ = lq, r1_ = 32 + lq;
#pragma unroll
      for (int s = 0; s < 8; s++) {
        short8 kf0 = *(const short8*)(&Ks[r0_][((s * 2 + hi) ^ (r0_ & 7)) * 8]);
        sac0 = __builtin_amdgcn_mfma_f32_32x32x16_bf16(kf0, qf[s], sac0, 0, 0, 0);
      }
#pragma unroll
      for (int s = 0; s < 8; s++) {
        short8 kf1 = *(const short8*)(&Ks[r1_][((s * 2 + hi) ^ (r1_ & 7)) * 8]);
        sac1 = __builtin_amdgcn_mfma_f32_32x32x16_bf16(kf1, qf[s], sac1, 0, 0, 0);
      }
    }
    __builtin_amdgcn_s_setprio(0);

    float p[32];
    const bool maskit = islast && (kv == niter - 1);
    if (maskit) {
#pragma unroll
      for (int r = 0; r < 16; r++) {
        int kvg = k0 + (r & 3) + 8 * (r >> 2) + 4 * hi;
        p[r] = (kvg <= qrow) ? exp2f(sac0[r] * SCALE2) : 0.0f;
      }
#pragma unroll
      for (int r = 0; r < 16; r++) {
        int kvg = k0 + 32 + (r & 3) + 8 * (r >> 2) + 4 * hi;
        p[16 + r] = (kvg <= qrow) ? exp2f(sac1[r] * SCALE2) : 0.0f;
      }
    } else {
#pragma unroll
      for (int r = 0; r < 16; r++) p[r] = exp2f(sac0[r] * SCALE2);
#pragma unroll
      for (int r = 0; r < 16; r++) p[16 + r] = exp2f(sac1[r] * SCALE2);
    }
#pragma unroll
    for (int i = 0; i < 32; i++) lsum += p[i];

    union { unsigned int w[4]; short8 v; } pa[4];
#pragma unroll
    for (int s = 0; s < 4; s++) {
      const int b = s * 8;
      unsigned int cA0 = cvtpk_bf16(p[b + 0], p[b + 1]);
      unsigned int cA1 = cvtpk_bf16(p[b + 2], p[b + 3]);
      unsigned int cB0 = cvtpk_bf16(p[b + 4], p[b + 5]);
      unsigned int cB1 = cvtpk_bf16(p[b + 6], p[b + 7]);
      u32x2 s0 = __builtin_amdgcn_permlane32_swap(cA0, cB0, false, false);
      u32x2 s1 = __builtin_amdgcn_permlane32_swap(cA1, cB1, false, false);
      pa[s].w[0] = s0[0]; pa[s].w[1] = s1[0]; pa[s].w[2] = s0[1]; pa[s].w[3] = s1[1];
    }

    __builtin_amdgcn_s_setprio(1);
#pragma unroll
    for (int dt = 0; dt < 4; dt++) {
      const int d = dt * 32 + lq;
      const int dz = ((d >> 2) & 7) << 3;
#pragma unroll
      for (int s = 0; s < 4; s++) {
        short8 vf = *(const short8*)(&vt[d][(s * 16 + hi * 8) ^ dz]);
        oacc[dt] = __builtin_amdgcn_mfma_f32_32x32x16_bf16(pa[s].v, vf, oacc[dt], 0, 0, 0);
      }
    }
    __builtin_amdgcn_s_setprio(0);
    __syncthreads();
  }

#pragma unroll
  for (int dt = 0; dt < 4; dt++) {
    const int d = dt * 32 + lq;
#pragma unroll
    for (int r = 0; r < 16; r++) {
      int qrw = qr + (r & 3) + 8 * (r >> 2) + 4 * hi;
      unsafeAtomicAdd(&accO[(size_t)qrw * 768 + h * 128 + d], oacc[dt][r]);
    }
  }
  unsafeAtomicAdd(&accL[qrow * 6 + h], lsum);
}

// ---------------------------------------------------------------------------
// d_out FLOAT32: out0 = y@Wo^T [3145728 f32], out1 = v_residual [3145728].
// Workspace (r12 layout, 37.9 MB): xb@0, qb, kb, vb (u16), accO+accL (f32).
// ---------------------------------------------------------------------------
extern "C" void kernel_launch(void* const* d_in, const int* in_sizes, int n_in,
                              void* d_out, int out_size, void* d_ws, size_t ws_size,
                              hipStream_t stream) {
  const float* x = (const float*)d_in[0];
  const float* vres = (const float*)d_in[1];
  const float* Wq = (const float*)d_in[2];
  const float* Wk = (const float*)d_in[3];
  const float* Wv = (const float*)d_in[4];
  const float* Wo = (const float*)d_in[5];
  const float* lamb = (const float*)d_in[6];
  const int* pos = (const int*)d_in[7];
  float* out = (float*)d_out;

  u16* xb = (u16*)d_ws;
  u16* qb = xb + 3145728;
  u16* kb = qb + 3145728;
  u16* vb = kb + 3145728;
  float* accO = (float*)((char*)d_ws + 25165824);
  float* accL = accO + 3145728;
  float* out1 = out + 3145728;

  r19_cvt_x<<<6168, 256, 0, stream>>>(x, xb, accO);
  r19_gemm_qkv<<<dim3(64, 6, 3), 256, 0, stream>>>(xb, Wq, Wk, Wv, qb, kb, vb);
  r19_normrope<<<6144, 256, 0, stream>>>(qb, kb, vb, vres, lamb, pos, out1);
  r19_attn<<<960, 128, 0, stream>>>(qb, kb, vb, accO, accL);
  r19_gemm_proj<<<dim3(64, 6), 256, 0, stream>>>(accO, accL, Wo, out);
}

// Round 20
// 144.445 us; speedup vs baseline: 1.4972x; 1.1058x over previous
//
#include <hip/hip_runtime.h>
#include <hip/hip_bf16.h>

typedef unsigned short u16;
typedef __attribute__((ext_vector_type(8))) short short8;
typedef __attribute__((ext_vector_type(4))) float f32x4;
typedef __attribute__((ext_vector_type(16))) float f32x16;
typedef __attribute__((ext_vector_type(2))) unsigned int u32x2;

#define MODEL 768
// 1/sqrt(128) * log2(e): exp(s/sqrt(128)) == exp2(s * SCALE2)
#define SCALE2 0.1275174137f

__device__ __forceinline__ float bf2f(u16 u) {
  unsigned int x = ((unsigned int)u) << 16;
  return __uint_as_float(x);
}
__device__ __forceinline__ u16 f2bf(float f) {
  unsigned int x = __float_as_uint(f);
  unsigned int r = (x + 0x7FFFu + ((x >> 16) & 1u)) >> 16;
  return (u16)r;
}
__device__ __forceinline__ void lds_ld16(const u16* g, u16* l) {
  __builtin_amdgcn_global_load_lds((const __attribute__((address_space(1))) void*)g,
                                   (__attribute__((address_space(3))) void*)l, 16, 0, 0);
}
__device__ __forceinline__ unsigned int cvtpk_bf16(float lo, float hi_) {
  unsigned int r;
  asm("v_cvt_pk_bf16_f32 %0, %1, %2" : "=v"(r) : "v"(lo), "v"(hi_));
  return r;
}

// ---------------------------------------------------------------------------
// Kernel 1: convert x f32->bf16 (786432 f4 units) AND Wq/Wk/Wv f32->bf16
// (3 x 147456 f4 units) into the accO region (dead until attn).
// Grid 4800 x 256.
// ---------------------------------------------------------------------------
__global__ __launch_bounds__(256) void r20_cvt(const float* __restrict__ x,
                                               const float* __restrict__ wq,
                                               const float* __restrict__ wk,
                                               const float* __restrict__ wv,
                                               u16* __restrict__ xb,
                                               u16* __restrict__ wqb,
                                               u16* __restrict__ wkb,
                                               u16* __restrict__ wvb) {
  int i = blockIdx.x * 256 + threadIdx.x;
  const float* src;
  u16* dst;
  int j;
  if (i < 786432) { src = x; dst = xb; j = i; }
  else if (i < 933888) { src = wq; dst = wqb; j = i - 786432; }
  else if (i < 1081344) { src = wk; dst = wkb; j = i - 933888; }
  else { src = wv; dst = wvb; j = i - 1081344; }
  float4 v = ((const float4*)src)[j];
  ushort4 o;
  o.x = f2bf(v.x); o.y = f2bf(v.y); o.z = f2bf(v.z); o.w = f2bf(v.w);
  ((ushort4*)dst)[j] = o;
}

// ---------------------------------------------------------------------------
// GEMM QKV, 64-ROW TILES, ALL-gload_lds staging: C = A_bf16 * Wb_bf16^T.
// Tile 64x128, BK=32, 4 waves (2x2, each 32x64).  A: 1 issue/wave;
// B: 2 issues/wave (pre-converted bf16 W).  Grid (64,6,3) = 1152 blocks.
// ---------------------------------------------------------------------------
__global__ __launch_bounds__(256) void r20_gemm_qkv(const u16* __restrict__ A,
                                                    const u16* __restrict__ W0,
                                                    const u16* __restrict__ W1,
                                                    const u16* __restrict__ W2,
                                                    u16* __restrict__ C0,
                                                    u16* __restrict__ C1,
                                                    u16* __restrict__ C2) {
  const u16* Wb = (blockIdx.z == 0) ? W0 : (blockIdx.z == 1) ? W1 : W2;
  u16* C = (blockIdx.z == 0) ? C0 : (blockIdx.z == 1) ? C1 : C2;
  __shared__ u16 As[64 * 32];
  __shared__ u16 Bs[128 * 32];
  const int tid = threadIdx.x;
  const int w = tid >> 6, l = tid & 63;
  const int lr = l & 15, lg = l >> 4;
  const int m0 = blockIdx.x * 64, n0 = blockIdx.y * 128;
  const int wr = (w >> 1) * 32, wc = (w & 1) * 64;
  const int sr = w * 16 + (l >> 2);   // A staging row (1 issue/wave)
  const int sc = (l & 3) * 8;         // 16B col block
  f32x4 acc[2][4] = {};
  for (int k0 = 0; k0 < 768; k0 += 32) {
    __syncthreads();
    lds_ld16(A + (size_t)(m0 + sr) * 768 + k0 + sc, As + w * 512);
#pragma unroll
    for (int i = 0; i < 2; i++) {
      int ii = w * 2 + i;                  // 0..7, 16 rows each
      int row = ii * 16 + (l >> 2);
      lds_ld16(Wb + (size_t)(n0 + row) * 768 + k0 + sc, Bs + ii * 512);
    }
    __syncthreads();
    short8 af[2], bfr[4];
#pragma unroll
    for (int mr = 0; mr < 2; mr++) af[mr] = *(const short8*)(As + (wr + mr * 16 + lr) * 32 + lg * 8);
#pragma unroll
    for (int nc = 0; nc < 4; nc++) bfr[nc] = *(const short8*)(Bs + (wc + nc * 16 + lr) * 32 + lg * 8);
#pragma unroll
    for (int mr = 0; mr < 2; mr++)
#pragma unroll
      for (int nc = 0; nc < 4; nc++)
        acc[mr][nc] = __builtin_amdgcn_mfma_f32_16x16x32_bf16(af[mr], bfr[nc], acc[mr][nc], 0, 0, 0);
  }
#pragma unroll
  for (int mr = 0; mr < 2; mr++)
#pragma unroll
    for (int nc = 0; nc < 4; nc++)
#pragma unroll
      for (int ri = 0; ri < 4; ri++) {
        int row = m0 + wr + mr * 16 + lg * 4 + ri;
        int col = n0 + wc + nc * 16 + lr;
        C[(size_t)row * 768 + col] = f2bf(acc[mr][nc][ri]);
      }
}

// ---------------------------------------------------------------------------
// GEMM PROJ (r19-exact), 64-row tiles: A = accO/accL (fused finalize),
// W f32 converted in staging, f32 out.  Grid (64,6) = 384 blocks.
// ---------------------------------------------------------------------------
__global__ __launch_bounds__(256) void r20_gemm_proj(const float* __restrict__ accO,
                                                     const float* __restrict__ accL,
                                                     const float* __restrict__ W,
                                                     float* __restrict__ C) {
  __shared__ u16 As[64 * 32];
  __shared__ u16 Bs[128 * 32];
  const int tid = threadIdx.x;
  const int w = tid >> 6, l = tid & 63;
  const int lr = l & 15, lg = l >> 4;
  const int m0 = blockIdx.x * 64, n0 = blockIdx.y * 128;
  const int wr = (w >> 1) * 32, wc = (w & 1) * 64;
  const int arow = tid >> 2;
  const int aoff = (tid & 3) * 8;
  const int qrow = tid >> 1;
  const int qoff = (tid & 1) * 16;
  f32x4 acc[2][4] = {};
  for (int k0 = 0; k0 < 768; k0 += 32) {
    __syncthreads();
    {
      const float* ap = accO + (size_t)(m0 + arow) * 768 + k0 + aoff;
      float rl = 1.0f / accL[(m0 + arow) * 6 + (k0 >> 7)];
      u16* dp = As + arow * 32 + aoff;
      float4 f0 = ((const float4*)ap)[0];
      float4 f1 = ((const float4*)ap)[1];
      ushort4 b0, b1;
      b0.x = f2bf(f0.x * rl); b0.y = f2bf(f0.y * rl);
      b0.z = f2bf(f0.z * rl); b0.w = f2bf(f0.w * rl);
      b1.x = f2bf(f1.x * rl); b1.y = f2bf(f1.y * rl);
      b1.z = f2bf(f1.z * rl); b1.w = f2bf(f1.w * rl);
      *(ushort4*)(dp) = b0;
      *(ushort4*)(dp + 4) = b1;
      const float* wp = W + (size_t)(n0 + qrow) * 768 + k0 + qoff;
      u16* bp = Bs + qrow * 32 + qoff;
#pragma unroll
      for (int q = 0; q < 4; q++) {
        float4 f = ((const float4*)wp)[q];
        ushort4 b;
        b.x = f2bf(f.x); b.y = f2bf(f.y); b.z = f2bf(f.z); b.w = f2bf(f.w);
        *(ushort4*)(bp + q * 4) = b;
      }
    }
    __syncthreads();
    short8 af[2], bfr[4];
#pragma unroll
    for (int mr = 0; mr < 2; mr++) af[mr] = *(const short8*)(As + (wr + mr * 16 + lr) * 32 + lg * 8);
#pragma unroll
    for (int nc = 0; nc < 4; nc++) bfr[nc] = *(const short8*)(Bs + (wc + nc * 16 + lr) * 32 + lg * 8);
#pragma unroll
    for (int mr = 0; mr < 2; mr++)
#pragma unroll
      for (int nc = 0; nc < 4; nc++)
        acc[mr][nc] = __builtin_amdgcn_mfma_f32_16x16x32_bf16(af[mr], bfr[nc], acc[mr][nc], 0, 0, 0);
  }
#pragma unroll
  for (int mr = 0; mr < 2; mr++)
#pragma unroll
    for (int nc = 0; nc < 4; nc++)
#pragma unroll
      for (int ri = 0; ri < 4; ri++) {
        int row = m0 + wr + mr * 16 + lg * 4 + ri;
        int col = n0 + wc + nc * 16 + lr;
        C[(size_t)row * 768 + col] = acc[mr][nc][ri];
      }
}

// ---------------------------------------------------------------------------
// Kernel 3: fused RMS-norm + rotary (Q,K) + lambda-mix (V) + out1 copy
// + accO/accL zeroing (W-bf16 aliases in that region are dead by now).
// ---------------------------------------------------------------------------
__global__ __launch_bounds__(256) void r20_normrope(u16* __restrict__ qb,
                                                    u16* __restrict__ kb,
                                                    u16* __restrict__ vb,
                                                    const float* __restrict__ vres,
                                                    const float* __restrict__ lambp,
                                                    const int* __restrict__ pos,
                                                    float* __restrict__ out1,
                                                    float* __restrict__ accZ) {
  // zero accO/accL: 792576 float4 units spread over the first 3097 blocks
  {
    int gid = blockIdx.x * 256 + threadIdx.x;
    if (gid < 792576) {
      float4 z = {0.0f, 0.0f, 0.0f, 0.0f};
      ((float4*)accZ)[gid] = z;
    }
  }
  const int wg = blockIdx.x * 4 + (threadIdx.x >> 6);
  const int l = threadIdx.x & 63;
  const int t = wg / 6;
  const int h = wg - t * 6;
  const size_t base = (size_t)t * MODEL + h * 128;
  const float EPS = 1.1920928955078125e-07f;

  float c = 1.0f, sn = 0.0f;
  if (l < 32) {
    float af = exp2f(-10.0f * (float)l * (1.0f / 31.0f));
    float th = (float)pos[t] * af;
    sincosf(th, &sn, &c);
  }
  {
    float a = bf2f(qb[base + l]), b = bf2f(qb[base + 64 + l]);
    float ss = a * a + b * b;
#pragma unroll
    for (int off = 32; off; off >>= 1) ss += __shfl_xor(ss, off);
    float r = rsqrtf(ss * (1.0f / 128.0f) + EPS);
    float an = a * r, bn = b * r;
    qb[base + l] = f2bf(an * c + bn * sn);
    qb[base + 64 + l] = f2bf(bn * c - an * sn);
  }
  {
    float a = bf2f(kb[base + l]), b = bf2f(kb[base + 64 + l]);
    float ss = a * a + b * b;
#pragma unroll
    for (int off = 32; off; off >>= 1) ss += __shfl_xor(ss, off);
    float r = rsqrtf(ss * (1.0f / 128.0f) + EPS);
    float an = a * r, bn = b * r;
    kb[base + l] = f2bf(an * c + bn * sn);
    kb[base + 64 + l] = f2bf(bn * c - an * sn);
  }
  {
    float lm = *lambp;
    float a = bf2f(vb[base + l]), b = bf2f(vb[base + 64 + l]);
    float ra = vres[base + l], rb = vres[base + 64 + l];
    vb[base + l] = f2bf((1.0f - lm) * a + lm * ra);
    vb[base + 64 + l] = f2bf((1.0f - lm) * b + lm * rb);
    out1[base + l] = ra;
    out1[base + 64 + l] = rb;
  }
}

// ---------------------------------------------------------------------------
// Kernel 4 (r12-exact, 6x reproduced ~73 us): causal flash attention,
// SPLIT-KV chunk 1024, 2-wave x 32 q-rows, 960 blocks longest-first,
// 32x32 MFMA swapped QK^T, in-register P, static-max softmax, f32 atomics.
// ---------------------------------------------------------------------------
__global__ __launch_bounds__(128, 2) void r20_attn(const u16* __restrict__ Q,
                                                   const u16* __restrict__ K,
                                                   const u16* __restrict__ V,
                                                   float* __restrict__ accO,
                                                   float* __restrict__ accL) {
  const int bx = blockIdx.x;          // 0..959
  const int h = bx / 160;
  const int u = 159 - (bx - h * 160);
  int qt, kc;
  if (u < 16)      { qt = u;                      kc = 0; }
  else if (u < 48) { int v = u - 16; qt = 16 + (v >> 1); kc = v & 1; }
  else if (u < 96) { int v = u - 48; int q3 = v / 3; qt = 32 + q3; kc = v - 3 * q3; }
  else             { int v = u - 96; qt = 48 + (v >> 2); kc = v & 3; }
  const int rowmax = 64 * qt + 63;
  const int c0 = kc << 10;
  const bool islast = (c0 + 1024 > rowmax);
  const int cend = islast ? (rowmax + 1) : (c0 + 1024);
  const int niter = (cend - c0) >> 6;

  const int tid = threadIdx.x;
  const int wv = tid >> 6, l = tid & 63;
  const int lq = l & 31;
  const int hi = l >> 5;

  __shared__ u16 Ks[64][128];
  __shared__ u16 vt[128][72];

  const int c_ = tid & 31, cc = c_ * 4, g = tid >> 5;
  const int vswz = (c_ & 7) << 3;

  const int qr = qt * 64 + wv * 32;
  const int qrow = qr + lq;

  short8 qf[8];
  {
    const u16* qp = Q + (size_t)qrow * 768 + h * 128 + hi * 8;
#pragma unroll
    for (int s = 0; s < 8; s++) qf[s] = *(const short8*)(qp + s * 16);
  }
  f32x16 oacc[4] = {};
  float lsum = 0.0f;

  for (int kv = 0; kv < niter; kv++) {
    const int k0 = c0 + kv * 64;

#pragma unroll
    for (int i = 0; i < 8; i++) {
      int rbase = wv * 32 + i * 4;
      int row = rbase + (l >> 4);
      int blk = (l & 15) ^ (row & 7);
      lds_ld16(K + (size_t)(k0 + row) * 768 + h * 128 + blk * 8, &Ks[rbase][0]);
    }
#pragma unroll
    for (int it = 0; it < 8; it++) {
      int rloc = 2 * (g + 4 * it);
      ushort4 va = *(const ushort4*)(V + (size_t)(k0 + rloc) * 768 + h * 128 + cc);
      ushort4 vb = *(const ushort4*)(V + (size_t)(k0 + rloc + 1) * 768 + h * 128 + cc);
      int rs = rloc ^ vswz;
      u16 a0[4] = {va.x, va.y, va.z, va.w};
      u16 b0[4] = {vb.x, vb.y, vb.z, vb.w};
#pragma unroll
      for (int q = 0; q < 4; q++) {
        ushort2 t2; t2.x = a0[q]; t2.y = b0[q];
        *(ushort2*)&vt[cc + q][rs] = t2;
      }
    }
    __syncthreads();

    f32x16 sac0 = {}, sac1 = {};
    __builtin_amdgcn_s_setprio(1);
    {
      const int r0_ = lq, r1_ = 32 + lq;
#pragma unroll
      for (int s = 0; s < 8; s++) {
        short8 kf0 = *(const short8*)(&Ks[r0_][((s * 2 + hi) ^ (r0_ & 7)) * 8]);
        sac0 = __builtin_amdgcn_mfma_f32_32x32x16_bf16(kf0, qf[s], sac0, 0, 0, 0);
      }
#pragma unroll
      for (int s = 0; s < 8; s++) {
        short8 kf1 = *(const short8*)(&Ks[r1_][((s * 2 + hi) ^ (r1_ & 7)) * 8]);
        sac1 = __builtin_amdgcn_mfma_f32_32x32x16_bf16(kf1, qf[s], sac1, 0, 0, 0);
      }
    }
    __builtin_amdgcn_s_setprio(0);

    float p[32];
    const bool maskit = islast && (kv == niter - 1);
    if (maskit) {
#pragma unroll
      for (int r = 0; r < 16; r++) {
        int kvg = k0 + (r & 3) + 8 * (r >> 2) + 4 * hi;
        p[r] = (kvg <= qrow) ? exp2f(sac0[r] * SCALE2) : 0.0f;
      }
#pragma unroll
      for (int r = 0; r < 16; r++) {
        int kvg = k0 + 32 + (r & 3) + 8 * (r >> 2) + 4 * hi;
        p[16 + r] = (kvg <= qrow) ? exp2f(sac1[r] * SCALE2) : 0.0f;
      }
    } else {
#pragma unroll
      for (int r = 0; r < 16; r++) p[r] = exp2f(sac0[r] * SCALE2);
#pragma unroll
      for (int r = 0; r < 16; r++) p[16 + r] = exp2f(sac1[r] * SCALE2);
    }
#pragma unroll
    for (int i = 0; i < 32; i++) lsum += p[i];

    union { unsigned int w[4]; short8 v; } pa[4];
#pragma unroll
    for (int s = 0; s < 4; s++) {
      const int b = s * 8;
      unsigned int cA0 = cvtpk_bf16(p[b + 0], p[b + 1]);
      unsigned int cA1 = cvtpk_bf16(p[b + 2], p[b + 3]);
      unsigned int cB0 = cvtpk_bf16(p[b + 4], p[b + 5]);
      unsigned int cB1 = cvtpk_bf16(p[b + 6], p[b + 7]);
      u32x2 s0 = __builtin_amdgcn_permlane32_swap(cA0, cB0, false, false);
      u32x2 s1 = __builtin_amdgcn_permlane32_swap(cA1, cB1, false, false);
      pa[s].w[0] = s0[0]; pa[s].w[1] = s1[0]; pa[s].w[2] = s0[1]; pa[s].w[3] = s1[1];
    }

    __builtin_amdgcn_s_setprio(1);
#pragma unroll
    for (int dt = 0; dt < 4; dt++) {
      const int d = dt * 32 + lq;
      const int dz = ((d >> 2) & 7) << 3;
#pragma unroll
      for (int s = 0; s < 4; s++) {
        short8 vf = *(const short8*)(&vt[d][(s * 16 + hi * 8) ^ dz]);
        oacc[dt] = __builtin_amdgcn_mfma_f32_32x32x16_bf16(pa[s].v, vf, oacc[dt], 0, 0, 0);
      }
    }
    __builtin_amdgcn_s_setprio(0);
    __syncthreads();
  }

#pragma unroll
  for (int dt = 0; dt < 4; dt++) {
    const int d = dt * 32 + lq;
#pragma unroll
    for (int r = 0; r < 16; r++) {
      int qrw = qr + (r & 3) + 8 * (r >> 2) + 4 * hi;
      unsafeAtomicAdd(&accO[(size_t)qrw * 768 + h * 128 + d], oacc[dt][r]);
    }
  }
  unsafeAtomicAdd(&accL[qrow * 6 + h], lsum);
}

// ---------------------------------------------------------------------------
// d_out FLOAT32: out0 = y@Wo^T [3145728 f32], out1 = v_residual [3145728].
// Workspace (37.9 MB): xb@0, qb, kb, vb (u16), accO+accL (f32).
// Wq/Wk/Wv bf16 alias the accO region (dead until normrope zeroes it).
// ---------------------------------------------------------------------------
extern "C" void kernel_launch(void* const* d_in, const int* in_sizes, int n_in,
                              void* d_out, int out_size, void* d_ws, size_t ws_size,
                              hipStream_t stream) {
  const float* x = (const float*)d_in[0];
  const float* vres = (const float*)d_in[1];
  const float* Wq = (const float*)d_in[2];
  const float* Wk = (const float*)d_in[3];
  const float* Wv = (const float*)d_in[4];
  const float* Wo = (const float*)d_in[5];
  const float* lamb = (const float*)d_in[6];
  const int* pos = (const int*)d_in[7];
  float* out = (float*)d_out;

  u16* xb = (u16*)d_ws;
  u16* qb = xb + 3145728;
  u16* kb = qb + 3145728;
  u16* vb = kb + 3145728;
  float* accO = (float*)((char*)d_ws + 25165824);
  float* accL = accO + 3145728;
  u16* wqb = (u16*)accO;            // aliases: dead before accO zeroing
  u16* wkb = wqb + 589824;
  u16* wvb = wkb + 589824;
  float* out1 = out + 3145728;

  r20_cvt<<<4800, 256, 0, stream>>>(x, Wq, Wk, Wv, xb, wqb, wkb, wvb);
  r20_gemm_qkv<<<dim3(64, 6, 3), 256, 0, stream>>>(xb, wqb, wkb, wvb, qb, kb, vb);
  r20_normrope<<<6144, 256, 0, stream>>>(qb, kb, vb, vres, lamb, pos, out1, accO);
  r20_attn<<<960, 128, 0, stream>>>(qb, kb, vb, accO, accL);
  r20_gemm_proj<<<dim3(64, 6), 256, 0, stream>>>(accO, accL, Wo, out);
}

// Round 21
// 141.016 us; speedup vs baseline: 1.5336x; 1.0243x over previous
//
#include <hip/hip_runtime.h>
#include <hip/hip_bf16.h>

typedef unsigned short u16;
typedef __attribute__((ext_vector_type(8))) short short8;
typedef __attribute__((ext_vector_type(4))) float f32x4;
typedef __attribute__((ext_vector_type(16))) float f32x16;
typedef __attribute__((ext_vector_type(2))) unsigned int u32x2;

#define MODEL 768
// 1/sqrt(128) * log2(e): exp(s/sqrt(128)) == exp2(s * SCALE2)
#define SCALE2 0.1275174137f

__device__ __forceinline__ float bf2f(u16 u) {
  unsigned int x = ((unsigned int)u) << 16;
  return __uint_as_float(x);
}
__device__ __forceinline__ u16 f2bf(float f) {
  unsigned int x = __float_as_uint(f);
  unsigned int r = (x + 0x7FFFu + ((x >> 16) & 1u)) >> 16;
  return (u16)r;
}
__device__ __forceinline__ void lds_ld16(const u16* g, u16* l) {
  __builtin_amdgcn_global_load_lds((const __attribute__((address_space(1))) void*)g,
                                   (__attribute__((address_space(3))) void*)l, 16, 0, 0);
}
__device__ __forceinline__ unsigned int cvtpk_bf16(float lo, float hi_) {
  unsigned int r;
  asm("v_cvt_pk_bf16_f32 %0, %1, %2" : "=v"(r) : "v"(lo), "v"(hi_));
  return r;
}

// ---------------------------------------------------------------------------
// Kernel 1 (r20-exact): convert x f32->bf16 AND Wq/Wk/Wv f32->bf16 into the
// accO region (dead until attn).  Grid 4800 x 256.
// ---------------------------------------------------------------------------
__global__ __launch_bounds__(256) void r21_cvt(const float* __restrict__ x,
                                               const float* __restrict__ wq,
                                               const float* __restrict__ wk,
                                               const float* __restrict__ wv,
                                               u16* __restrict__ xb,
                                               u16* __restrict__ wqb,
                                               u16* __restrict__ wkb,
                                               u16* __restrict__ wvb) {
  int i = blockIdx.x * 256 + threadIdx.x;
  const float* src;
  u16* dst;
  int j;
  if (i < 786432) { src = x; dst = xb; j = i; }
  else if (i < 933888) { src = wq; dst = wqb; j = i - 786432; }
  else if (i < 1081344) { src = wk; dst = wkb; j = i - 933888; }
  else { src = wv; dst = wvb; j = i - 1081344; }
  float4 v = ((const float4*)src)[j];
  ushort4 o;
  o.x = f2bf(v.x); o.y = f2bf(v.y); o.z = f2bf(v.z); o.w = f2bf(v.w);
  ((ushort4*)dst)[j] = o;
}

// ---------------------------------------------------------------------------
// GEMM QKV (r20-exact), 64-row tiles, all-gload_lds staging.
// ---------------------------------------------------------------------------
__global__ __launch_bounds__(256) void r21_gemm_qkv(const u16* __restrict__ A,
                                                    const u16* __restrict__ W0,
                                                    const u16* __restrict__ W1,
                                                    const u16* __restrict__ W2,
                                                    u16* __restrict__ C0,
                                                    u16* __restrict__ C1,
                                                    u16* __restrict__ C2) {
  const u16* Wb = (blockIdx.z == 0) ? W0 : (blockIdx.z == 1) ? W1 : W2;
  u16* C = (blockIdx.z == 0) ? C0 : (blockIdx.z == 1) ? C1 : C2;
  __shared__ u16 As[64 * 32];
  __shared__ u16 Bs[128 * 32];
  const int tid = threadIdx.x;
  const int w = tid >> 6, l = tid & 63;
  const int lr = l & 15, lg = l >> 4;
  const int m0 = blockIdx.x * 64, n0 = blockIdx.y * 128;
  const int wr = (w >> 1) * 32, wc = (w & 1) * 64;
  const int sr = w * 16 + (l >> 2);
  const int sc = (l & 3) * 8;
  f32x4 acc[2][4] = {};
  for (int k0 = 0; k0 < 768; k0 += 32) {
    __syncthreads();
    lds_ld16(A + (size_t)(m0 + sr) * 768 + k0 + sc, As + w * 512);
#pragma unroll
    for (int i = 0; i < 2; i++) {
      int ii = w * 2 + i;
      int row = ii * 16 + (l >> 2);
      lds_ld16(Wb + (size_t)(n0 + row) * 768 + k0 + sc, Bs + ii * 512);
    }
    __syncthreads();
    short8 af[2], bfr[4];
#pragma unroll
    for (int mr = 0; mr < 2; mr++) af[mr] = *(const short8*)(As + (wr + mr * 16 + lr) * 32 + lg * 8);
#pragma unroll
    for (int nc = 0; nc < 4; nc++) bfr[nc] = *(const short8*)(Bs + (wc + nc * 16 + lr) * 32 + lg * 8);
#pragma unroll
    for (int mr = 0; mr < 2; mr++)
#pragma unroll
      for (int nc = 0; nc < 4; nc++)
        acc[mr][nc] = __builtin_amdgcn_mfma_f32_16x16x32_bf16(af[mr], bfr[nc], acc[mr][nc], 0, 0, 0);
  }
#pragma unroll
  for (int mr = 0; mr < 2; mr++)
#pragma unroll
    for (int nc = 0; nc < 4; nc++)
#pragma unroll
      for (int ri = 0; ri < 4; ri++) {
        int row = m0 + wr + mr * 16 + lg * 4 + ri;
        int col = n0 + wc + nc * 16 + lr;
        C[(size_t)row * 768 + col] = f2bf(acc[mr][nc][ri]);
      }
}

// ---------------------------------------------------------------------------
// GEMM PROJ, 64-row tiles, bf16-W via gload_lds (same B-panel as qkv):
// A = accO/accL (fused finalize) staged f32->bf16; f32 out to d_out.
// ---------------------------------------------------------------------------
__global__ __launch_bounds__(256) void r21_gemm_proj(const float* __restrict__ accO,
                                                     const float* __restrict__ accL,
                                                     const u16* __restrict__ Wb,
                                                     float* __restrict__ C) {
  __shared__ u16 As[64 * 32];
  __shared__ u16 Bs[128 * 32];
  const int tid = threadIdx.x;
  const int w = tid >> 6, l = tid & 63;
  const int lr = l & 15, lg = l >> 4;
  const int m0 = blockIdx.x * 64, n0 = blockIdx.y * 128;
  const int wr = (w >> 1) * 32, wc = (w & 1) * 64;
  const int arow = tid >> 2;
  const int aoff = (tid & 3) * 8;
  const int sc = (l & 3) * 8;
  f32x4 acc[2][4] = {};
  for (int k0 = 0; k0 < 768; k0 += 32) {
    __syncthreads();
    {
      const float* ap = accO + (size_t)(m0 + arow) * 768 + k0 + aoff;
      float rl = 1.0f / accL[(m0 + arow) * 6 + (k0 >> 7)];
      u16* dp = As + arow * 32 + aoff;
      float4 f0 = ((const float4*)ap)[0];
      float4 f1 = ((const float4*)ap)[1];
      ushort4 b0, b1;
      b0.x = f2bf(f0.x * rl); b0.y = f2bf(f0.y * rl);
      b0.z = f2bf(f0.z * rl); b0.w = f2bf(f0.w * rl);
      b1.x = f2bf(f1.x * rl); b1.y = f2bf(f1.y * rl);
      b1.z = f2bf(f1.z * rl); b1.w = f2bf(f1.w * rl);
      *(ushort4*)(dp) = b0;
      *(ushort4*)(dp + 4) = b1;
    }
#pragma unroll
    for (int i = 0; i < 2; i++) {
      int ii = w * 2 + i;
      int row = ii * 16 + (l >> 2);
      lds_ld16(Wb + (size_t)(n0 + row) * 768 + k0 + sc, Bs + ii * 512);
    }
    __syncthreads();
    short8 af[2], bfr[4];
#pragma unroll
    for (int mr = 0; mr < 2; mr++) af[mr] = *(const short8*)(As + (wr + mr * 16 + lr) * 32 + lg * 8);
#pragma unroll
    for (int nc = 0; nc < 4; nc++) bfr[nc] = *(const short8*)(Bs + (wc + nc * 16 + lr) * 32 + lg * 8);
#pragma unroll
    for (int mr = 0; mr < 2; mr++)
#pragma unroll
      for (int nc = 0; nc < 4; nc++)
        acc[mr][nc] = __builtin_amdgcn_mfma_f32_16x16x32_bf16(af[mr], bfr[nc], acc[mr][nc], 0, 0, 0);
  }
#pragma unroll
  for (int mr = 0; mr < 2; mr++)
#pragma unroll
    for (int nc = 0; nc < 4; nc++)
#pragma unroll
      for (int ri = 0; ri < 4; ri++) {
        int row = m0 + wr + mr * 16 + lg * 4 + ri;
        int col = n0 + wc + nc * 16 + lr;
        C[(size_t)row * 768 + col] = acc[mr][nc][ri];
      }
}

// ---------------------------------------------------------------------------
// Kernel 3: fused RMS-norm + rotary (Q,K) + lambda-mix (V) + out1 copy
// + accO/accL zeroing + Wo f32->bf16 conversion into xb (dead after qkv).
// ---------------------------------------------------------------------------
__global__ __launch_bounds__(256) void r21_normrope(u16* __restrict__ qb,
                                                    u16* __restrict__ kb,
                                                    u16* __restrict__ vb,
                                                    const float* __restrict__ vres,
                                                    const float* __restrict__ lambp,
                                                    const int* __restrict__ pos,
                                                    float* __restrict__ out1,
                                                    float* __restrict__ accZ,
                                                    const float* __restrict__ wo,
                                                    u16* __restrict__ wob) {
  {
    int gid = blockIdx.x * 256 + threadIdx.x;
    if (gid < 792576) {
      float4 z = {0.0f, 0.0f, 0.0f, 0.0f};
      ((float4*)accZ)[gid] = z;
    } else if (gid < 792576 + 147456) {
      int j = gid - 792576;
      float4 v = ((const float4*)wo)[j];
      ushort4 o;
      o.x = f2bf(v.x); o.y = f2bf(v.y); o.z = f2bf(v.z); o.w = f2bf(v.w);
      ((ushort4*)wob)[j] = o;
    }
  }
  const int wg = blockIdx.x * 4 + (threadIdx.x >> 6);
  const int l = threadIdx.x & 63;
  const int t = wg / 6;
  const int h = wg - t * 6;
  const size_t base = (size_t)t * MODEL + h * 128;
  const float EPS = 1.1920928955078125e-07f;

  float c = 1.0f, sn = 0.0f;
  if (l < 32) {
    float af = exp2f(-10.0f * (float)l * (1.0f / 31.0f));
    float th = (float)pos[t] * af;
    sincosf(th, &sn, &c);
  }
  {
    float a = bf2f(qb[base + l]), b = bf2f(qb[base + 64 + l]);
    float ss = a * a + b * b;
#pragma unroll
    for (int off = 32; off; off >>= 1) ss += __shfl_xor(ss, off);
    float r = rsqrtf(ss * (1.0f / 128.0f) + EPS);
    float an = a * r, bn = b * r;
    qb[base + l] = f2bf(an * c + bn * sn);
    qb[base + 64 + l] = f2bf(bn * c - an * sn);
  }
  {
    float a = bf2f(kb[base + l]), b = bf2f(kb[base + 64 + l]);
    float ss = a * a + b * b;
#pragma unroll
    for (int off = 32; off; off >>= 1) ss += __shfl_xor(ss, off);
    float r = rsqrtf(ss * (1.0f / 128.0f) + EPS);
    float an = a * r, bn = b * r;
    kb[base + l] = f2bf(an * c + bn * sn);
    kb[base + 64 + l] = f2bf(bn * c - an * sn);
  }
  {
    float lm = *lambp;
    float a = bf2f(vb[base + l]), b = bf2f(vb[base + 64 + l]);
    float ra = vres[base + l], rb = vres[base + 64 + l];
    vb[base + l] = f2bf((1.0f - lm) * a + lm * ra);
    vb[base + 64 + l] = f2bf((1.0f - lm) * b + lm * rb);
    out1[base + l] = ra;
    out1[base + 64 + l] = rb;
  }
}

// ---------------------------------------------------------------------------
// Kernel 4 (r12-exact, 7x reproduced ~73 us): causal flash attention,
// SPLIT-KV chunk 1024, 2-wave x 32 q-rows, 960 blocks longest-first,
// 32x32 MFMA swapped QK^T, in-register P, static-max softmax, f32 atomics.
// ---------------------------------------------------------------------------
__global__ __launch_bounds__(128, 2) void r21_attn(const u16* __restrict__ Q,
                                                   const u16* __restrict__ K,
                                                   const u16* __restrict__ V,
                                                   float* __restrict__ accO,
                                                   float* __restrict__ accL) {
  const int bx = blockIdx.x;          // 0..959
  const int h = bx / 160;
  const int u = 159 - (bx - h * 160);
  int qt, kc;
  if (u < 16)      { qt = u;                      kc = 0; }
  else if (u < 48) { int v = u - 16; qt = 16 + (v >> 1); kc = v & 1; }
  else if (u < 96) { int v = u - 48; int q3 = v / 3; qt = 32 + q3; kc = v - 3 * q3; }
  else             { int v = u - 96; qt = 48 + (v >> 2); kc = v & 3; }
  const int rowmax = 64 * qt + 63;
  const int c0 = kc << 10;
  const bool islast = (c0 + 1024 > rowmax);
  const int cend = islast ? (rowmax + 1) : (c0 + 1024);
  const int niter = (cend - c0) >> 6;

  const int tid = threadIdx.x;
  const int wv = tid >> 6, l = tid & 63;
  const int lq = l & 31;
  const int hi = l >> 5;

  __shared__ u16 Ks[64][128];
  __shared__ u16 vt[128][72];

  const int c_ = tid & 31, cc = c_ * 4, g = tid >> 5;
  const int vswz = (c_ & 7) << 3;

  const int qr = qt * 64 + wv * 32;
  const int qrow = qr + lq;

  short8 qf[8];
  {
    const u16* qp = Q + (size_t)qrow * 768 + h * 128 + hi * 8;
#pragma unroll
    for (int s = 0; s < 8; s++) qf[s] = *(const short8*)(qp + s * 16);
  }
  f32x16 oacc[4] = {};
  float lsum = 0.0f;

  for (int kv = 0; kv < niter; kv++) {
    const int k0 = c0 + kv * 64;

#pragma unroll
    for (int i = 0; i < 8; i++) {
      int rbase = wv * 32 + i * 4;
      int row = rbase + (l >> 4);
      int blk = (l & 15) ^ (row & 7);
      lds_ld16(K + (size_t)(k0 + row) * 768 + h * 128 + blk * 8, &Ks[rbase][0]);
    }
#pragma unroll
    for (int it = 0; it < 8; it++) {
      int rloc = 2 * (g + 4 * it);
      ushort4 va = *(const ushort4*)(V + (size_t)(k0 + rloc) * 768 + h * 128 + cc);
      ushort4 vb = *(const ushort4*)(V + (size_t)(k0 + rloc + 1) * 768 + h * 128 + cc);
      int rs = rloc ^ vswz;
      u16 a0[4] = {va.x, va.y, va.z, va.w};
      u16 b0[4] = {vb.x, vb.y, vb.z, vb.w};
#pragma unroll
      for (int q = 0; q < 4; q++) {
        ushort2 t2; t2.x = a0[q]; t2.y = b0[q];
        *(ushort2*)&vt[cc + q][rs] = t2;
      }
    }
    __syncthreads();

    f32x16 sac0 = {}, sac1 = {};
    __builtin_amdgcn_s_setprio(1);
    {
      const int r0_ = lq, r1_ = 32 + lq;
#pragma unroll
      for (int s = 0; s < 8; s++) {
        short8 kf0 = *(const short8*)(&Ks[r0_][((s * 2 + hi) ^ (r0_ & 7)) * 8]);
        sac0 = __builtin_amdgcn_mfma_f32_32x32x16_bf16(kf0, qf[s], sac0, 0, 0, 0);
      }
#pragma unroll
      for (int s = 0; s < 8; s++) {
        short8 kf1 = *(const short8*)(&Ks[r1_][((s * 2 + hi) ^ (r1_ & 7)) * 8]);
        sac1 = __builtin_amdgcn_mfma_f32_32x32x16_bf16(kf1, qf[s], sac1, 0, 0, 0);
      }
    }
    __builtin_amdgcn_s_setprio(0);

    float p[32];
    const bool maskit = islast && (kv == niter - 1);
    if (maskit) {
#pragma unroll
      for (int r = 0; r < 16; r++) {
        int kvg = k0 + (r & 3) + 8 * (r >> 2) + 4 * hi;
        p[r] = (kvg <= qrow) ? exp2f(sac0[r] * SCALE2) : 0.0f;
      }
#pragma unroll
      for (int r = 0; r < 16; r++) {
        int kvg = k0 + 32 + (r & 3) + 8 * (r >> 2) + 4 * hi;
        p[16 + r] = (kvg <= qrow) ? exp2f(sac1[r] * SCALE2) : 0.0f;
      }
    } else {
#pragma unroll
      for (int r = 0; r < 16; r++) p[r] = exp2f(sac0[r] * SCALE2);
#pragma unroll
      for (int r = 0; r < 16; r++) p[16 + r] = exp2f(sac1[r] * SCALE2);
    }
#pragma unroll
    for (int i = 0; i < 32; i++) lsum += p[i];

    union { unsigned int w[4]; short8 v; } pa[4];
#pragma unroll
    for (int s = 0; s < 4; s++) {
      const int b = s * 8;
      unsigned int cA0 = cvtpk_bf16(p[b + 0], p[b + 1]);
      unsigned int cA1 = cvtpk_bf16(p[b + 2], p[b + 3]);
      unsigned int cB0 = cvtpk_bf16(p[b + 4], p[b + 5]);
      unsigned int cB1 = cvtpk_bf16(p[b + 6], p[b + 7]);
      u32x2 s0 = __builtin_amdgcn_permlane32_swap(cA0, cB0, false, false);
      u32x2 s1 = __builtin_amdgcn_permlane32_swap(cA1, cB1, false, false);
      pa[s].w[0] = s0[0]; pa[s].w[1] = s1[0]; pa[s].w[2] = s0[1]; pa[s].w[3] = s1[1];
    }

    __builtin_amdgcn_s_setprio(1);
#pragma unroll
    for (int dt = 0; dt < 4; dt++) {
      const int d = dt * 32 + lq;
      const int dz = ((d >> 2) & 7) << 3;
#pragma unroll
      for (int s = 0; s < 4; s++) {
        short8 vf = *(const short8*)(&vt[d][(s * 16 + hi * 8) ^ dz]);
        oacc[dt] = __builtin_amdgcn_mfma_f32_32x32x16_bf16(pa[s].v, vf, oacc[dt], 0, 0, 0);
      }
    }
    __builtin_amdgcn_s_setprio(0);
    __syncthreads();
  }

#pragma unroll
  for (int dt = 0; dt < 4; dt++) {
    const int d = dt * 32 + lq;
#pragma unroll
    for (int r = 0; r < 16; r++) {
      int qrw = qr + (r & 3) + 8 * (r >> 2) + 4 * hi;
      unsafeAtomicAdd(&accO[(size_t)qrw * 768 + h * 128 + d], oacc[dt][r]);
    }
  }
  unsafeAtomicAdd(&accL[qrow * 6 + h], lsum);
}

// ---------------------------------------------------------------------------
// d_out FLOAT32: out0 = y@Wo^T [3145728 f32], out1 = v_residual [3145728].
// Workspace (37.9 MB): xb@0, qb, kb, vb (u16), accO+accL (f32).
// Wq/Wk/Wv bf16 alias accO (dead before zeroing); Wo bf16 aliases xb
// (dead after gemm_qkv, written by normrope, read by proj).
// ---------------------------------------------------------------------------
extern "C" void kernel_launch(void* const* d_in, const int* in_sizes, int n_in,
                              void* d_out, int out_size, void* d_ws, size_t ws_size,
                              hipStream_t stream) {
  const float* x = (const float*)d_in[0];
  const float* vres = (const float*)d_in[1];
  const float* Wq = (const float*)d_in[2];
  const float* Wk = (const float*)d_in[3];
  const float* Wv = (const float*)d_in[4];
  const float* Wo = (const float*)d_in[5];
  const float* lamb = (const float*)d_in[6];
  const int* pos = (const int*)d_in[7];
  float* out = (float*)d_out;

  u16* xb = (u16*)d_ws;
  u16* qb = xb + 3145728;
  u16* kb = qb + 3145728;
  u16* vb = kb + 3145728;
  float* accO = (float*)((char*)d_ws + 25165824);
  float* accL = accO + 3145728;
  u16* wqb = (u16*)accO;            // aliases accO: dead before zeroing
  u16* wkb = wqb + 589824;
  u16* wvb = wkb + 589824;
  u16* wob = xb;                    // aliases xb: dead after gemm_qkv
  float* out1 = out + 3145728;

  r21_cvt<<<4800, 256, 0, stream>>>(x, Wq, Wk, Wv, xb, wqb, wkb, wvb);
  r21_gemm_qkv<<<dim3(64, 6, 3), 256, 0, stream>>>(xb, wqb, wkb, wvb, qb, kb, vb);
  r21_normrope<<<6144, 256, 0, stream>>>(qb, kb, vb, vres, lamb, pos, out1,
                                         accO, Wo, wob);
  r21_attn<<<960, 128, 0, stream>>>(qb, kb, vb, accO, accL);
  r21_gemm_proj<<<dim3(64, 6), 256, 0, stream>>>(accO, accL, wob, out);
}

// Round 22
// 140.636 us; speedup vs baseline: 1.5378x; 1.0027x over previous
//
#include <hip/hip_runtime.h>
#include <hip/hip_bf16.h>

typedef unsigned short u16;
typedef __attribute__((ext_vector_type(8))) short short8;
typedef __attribute__((ext_vector_type(4))) float f32x4;
typedef __attribute__((ext_vector_type(16))) float f32x16;
typedef __attribute__((ext_vector_type(2))) unsigned int u32x2;

#define MODEL 768
// 1/sqrt(128) * log2(e): exp(s/sqrt(128)) == exp2(s * SCALE2)
#define SCALE2 0.1275174137f

__device__ __forceinline__ float bf2f(u16 u) {
  unsigned int x = ((unsigned int)u) << 16;
  return __uint_as_float(x);
}
__device__ __forceinline__ u16 f2bf(float f) {
  unsigned int x = __float_as_uint(f);
  unsigned int r = (x + 0x7FFFu + ((x >> 16) & 1u)) >> 16;
  return (u16)r;
}
__device__ __forceinline__ void lds_ld16(const u16* g, u16* l) {
  __builtin_amdgcn_global_load_lds((const __attribute__((address_space(1))) void*)g,
                                   (__attribute__((address_space(3))) void*)l, 16, 0, 0);
}
__device__ __forceinline__ unsigned int cvtpk_bf16(float lo, float hi_) {
  unsigned int r;
  asm("v_cvt_pk_bf16_f32 %0, %1, %2" : "=v"(r) : "v"(lo), "v"(hi_));
  return r;
}

// ---------------------------------------------------------------------------
// Kernel 1 (r21-exact): convert x f32->bf16 AND Wq/Wk/Wv f32->bf16 into the
// accO region (dead until attn).  Grid 4800 x 256.
// ---------------------------------------------------------------------------
__global__ __launch_bounds__(256) void r22_cvt(const float* __restrict__ x,
                                               const float* __restrict__ wq,
                                               const float* __restrict__ wk,
                                               const float* __restrict__ wv,
                                               u16* __restrict__ xb,
                                               u16* __restrict__ wqb,
                                               u16* __restrict__ wkb,
                                               u16* __restrict__ wvb) {
  int i = blockIdx.x * 256 + threadIdx.x;
  const float* src;
  u16* dst;
  int j;
  if (i < 786432) { src = x; dst = xb; j = i; }
  else if (i < 933888) { src = wq; dst = wqb; j = i - 786432; }
  else if (i < 1081344) { src = wk; dst = wkb; j = i - 933888; }
  else { src = wv; dst = wvb; j = i - 1081344; }
  float4 v = ((const float4*)src)[j];
  ushort4 o;
  o.x = f2bf(v.x); o.y = f2bf(v.y); o.z = f2bf(v.z); o.w = f2bf(v.w);
  ((ushort4*)dst)[j] = o;
}

// ---------------------------------------------------------------------------
// GEMM QKV (r20-exact), 64-row tiles, all-gload_lds staging.
// ---------------------------------------------------------------------------
__global__ __launch_bounds__(256) void r22_gemm_qkv(const u16* __restrict__ A,
                                                    const u16* __restrict__ W0,
                                                    const u16* __restrict__ W1,
                                                    const u16* __restrict__ W2,
                                                    u16* __restrict__ C0,
                                                    u16* __restrict__ C1,
                                                    u16* __restrict__ C2) {
  const u16* Wb = (blockIdx.z == 0) ? W0 : (blockIdx.z == 1) ? W1 : W2;
  u16* C = (blockIdx.z == 0) ? C0 : (blockIdx.z == 1) ? C1 : C2;
  __shared__ u16 As[64 * 32];
  __shared__ u16 Bs[128 * 32];
  const int tid = threadIdx.x;
  const int w = tid >> 6, l = tid & 63;
  const int lr = l & 15, lg = l >> 4;
  const int m0 = blockIdx.x * 64, n0 = blockIdx.y * 128;
  const int wr = (w >> 1) * 32, wc = (w & 1) * 64;
  const int sr = w * 16 + (l >> 2);
  const int sc = (l & 3) * 8;
  f32x4 acc[2][4] = {};
  for (int k0 = 0; k0 < 768; k0 += 32) {
    __syncthreads();
    lds_ld16(A + (size_t)(m0 + sr) * 768 + k0 + sc, As + w * 512);
#pragma unroll
    for (int i = 0; i < 2; i++) {
      int ii = w * 2 + i;
      int row = ii * 16 + (l >> 2);
      lds_ld16(Wb + (size_t)(n0 + row) * 768 + k0 + sc, Bs + ii * 512);
    }
    __syncthreads();
    short8 af[2], bfr[4];
#pragma unroll
    for (int mr = 0; mr < 2; mr++) af[mr] = *(const short8*)(As + (wr + mr * 16 + lr) * 32 + lg * 8);
#pragma unroll
    for (int nc = 0; nc < 4; nc++) bfr[nc] = *(const short8*)(Bs + (wc + nc * 16 + lr) * 32 + lg * 8);
#pragma unroll
    for (int mr = 0; mr < 2; mr++)
#pragma unroll
      for (int nc = 0; nc < 4; nc++)
        acc[mr][nc] = __builtin_amdgcn_mfma_f32_16x16x32_bf16(af[mr], bfr[nc], acc[mr][nc], 0, 0, 0);
  }
#pragma unroll
  for (int mr = 0; mr < 2; mr++)
#pragma unroll
    for (int nc = 0; nc < 4; nc++)
#pragma unroll
      for (int ri = 0; ri < 4; ri++) {
        int row = m0 + wr + mr * 16 + lg * 4 + ri;
        int col = n0 + wc + nc * 16 + lr;
        C[(size_t)row * 768 + col] = f2bf(acc[mr][nc][ri]);
      }
}

// ---------------------------------------------------------------------------
// GEMM PROJ (r21-exact), 64-row tiles, bf16-W via gload_lds:
// A = accO/accL (fused finalize) staged f32->bf16; f32 out to d_out.
// ---------------------------------------------------------------------------
__global__ __launch_bounds__(256) void r22_gemm_proj(const float* __restrict__ accO,
                                                     const float* __restrict__ accL,
                                                     const u16* __restrict__ Wb,
                                                     float* __restrict__ C) {
  __shared__ u16 As[64 * 32];
  __shared__ u16 Bs[128 * 32];
  const int tid = threadIdx.x;
  const int w = tid >> 6, l = tid & 63;
  const int lr = l & 15, lg = l >> 4;
  const int m0 = blockIdx.x * 64, n0 = blockIdx.y * 128;
  const int wr = (w >> 1) * 32, wc = (w & 1) * 64;
  const int arow = tid >> 2;
  const int aoff = (tid & 3) * 8;
  const int sc = (l & 3) * 8;
  f32x4 acc[2][4] = {};
  for (int k0 = 0; k0 < 768; k0 += 32) {
    __syncthreads();
    {
      const float* ap = accO + (size_t)(m0 + arow) * 768 + k0 + aoff;
      float rl = 1.0f / accL[(m0 + arow) * 6 + (k0 >> 7)];
      u16* dp = As + arow * 32 + aoff;
      float4 f0 = ((const float4*)ap)[0];
      float4 f1 = ((const float4*)ap)[1];
      ushort4 b0, b1;
      b0.x = f2bf(f0.x * rl); b0.y = f2bf(f0.y * rl);
      b0.z = f2bf(f0.z * rl); b0.w = f2bf(f0.w * rl);
      b1.x = f2bf(f1.x * rl); b1.y = f2bf(f1.y * rl);
      b1.z = f2bf(f1.z * rl); b1.w = f2bf(f1.w * rl);
      *(ushort4*)(dp) = b0;
      *(ushort4*)(dp + 4) = b1;
    }
#pragma unroll
    for (int i = 0; i < 2; i++) {
      int ii = w * 2 + i;
      int row = ii * 16 + (l >> 2);
      lds_ld16(Wb + (size_t)(n0 + row) * 768 + k0 + sc, Bs + ii * 512);
    }
    __syncthreads();
    short8 af[2], bfr[4];
#pragma unroll
    for (int mr = 0; mr < 2; mr++) af[mr] = *(const short8*)(As + (wr + mr * 16 + lr) * 32 + lg * 8);
#pragma unroll
    for (int nc = 0; nc < 4; nc++) bfr[nc] = *(const short8*)(Bs + (wc + nc * 16 + lr) * 32 + lg * 8);
#pragma unroll
    for (int mr = 0; mr < 2; mr++)
#pragma unroll
      for (int nc = 0; nc < 4; nc++)
        acc[mr][nc] = __builtin_amdgcn_mfma_f32_16x16x32_bf16(af[mr], bfr[nc], acc[mr][nc], 0, 0, 0);
  }
#pragma unroll
  for (int mr = 0; mr < 2; mr++)
#pragma unroll
    for (int nc = 0; nc < 4; nc++)
#pragma unroll
      for (int ri = 0; ri < 4; ri++) {
        int row = m0 + wr + mr * 16 + lg * 4 + ri;
        int col = n0 + wc + nc * 16 + lr;
        C[(size_t)row * 768 + col] = acc[mr][nc][ri];
      }
}

// ---------------------------------------------------------------------------
// Kernel 3: fused RMS-norm + rotary (Q,K) + lambda-mix (V) + out1 copy
// + accO/accL zeroing + Wo f32->bf16 into xb.  Q is PRE-SCALED by SCALE2
// (folded into its rsqrt) so attn's softmax needs no multiply.
// ---------------------------------------------------------------------------
__global__ __launch_bounds__(256) void r22_normrope(u16* __restrict__ qb,
                                                    u16* __restrict__ kb,
                                                    u16* __restrict__ vb,
                                                    const float* __restrict__ vres,
                                                    const float* __restrict__ lambp,
                                                    const int* __restrict__ pos,
                                                    float* __restrict__ out1,
                                                    float* __restrict__ accZ,
                                                    const float* __restrict__ wo,
                                                    u16* __restrict__ wob) {
  {
    int gid = blockIdx.x * 256 + threadIdx.x;
    if (gid < 792576) {
      float4 z = {0.0f, 0.0f, 0.0f, 0.0f};
      ((float4*)accZ)[gid] = z;
    } else if (gid < 792576 + 147456) {
      int j = gid - 792576;
      float4 v = ((const float4*)wo)[j];
      ushort4 o;
      o.x = f2bf(v.x); o.y = f2bf(v.y); o.z = f2bf(v.z); o.w = f2bf(v.w);
      ((ushort4*)wob)[j] = o;
    }
  }
  const int wg = blockIdx.x * 4 + (threadIdx.x >> 6);
  const int l = threadIdx.x & 63;
  const int t = wg / 6;
  const int h = wg - t * 6;
  const size_t base = (size_t)t * MODEL + h * 128;
  const float EPS = 1.1920928955078125e-07f;

  float c = 1.0f, sn = 0.0f;
  if (l < 32) {
    float af = exp2f(-10.0f * (float)l * (1.0f / 31.0f));
    float th = (float)pos[t] * af;
    sincosf(th, &sn, &c);
  }
  {
    float a = bf2f(qb[base + l]), b = bf2f(qb[base + 64 + l]);
    float ss = a * a + b * b;
#pragma unroll
    for (int off = 32; off; off >>= 1) ss += __shfl_xor(ss, off);
    // fold softmax scale*log2(e) into Q's normalizer
    float r = rsqrtf(ss * (1.0f / 128.0f) + EPS) * SCALE2;
    float an = a * r, bn = b * r;
    qb[base + l] = f2bf(an * c + bn * sn);
    qb[base + 64 + l] = f2bf(bn * c - an * sn);
  }
  {
    float a = bf2f(kb[base + l]), b = bf2f(kb[base + 64 + l]);
    float ss = a * a + b * b;
#pragma unroll
    for (int off = 32; off; off >>= 1) ss += __shfl_xor(ss, off);
    float r = rsqrtf(ss * (1.0f / 128.0f) + EPS);
    float an = a * r, bn = b * r;
    kb[base + l] = f2bf(an * c + bn * sn);
    kb[base + 64 + l] = f2bf(bn * c - an * sn);
  }
  {
    float lm = *lambp;
    float a = bf2f(vb[base + l]), b = bf2f(vb[base + 64 + l]);
    float ra = vres[base + l], rb = vres[base + 64 + l];
    vb[base + l] = f2bf((1.0f - lm) * a + lm * ra);
    vb[base + 64 + l] = f2bf((1.0f - lm) * b + lm * rb);
    out1[base + l] = ra;
    out1[base + 64 + l] = rb;
  }
}

// ---------------------------------------------------------------------------
// Kernel 4: causal flash attention (r12 structure).  r22 deltas:
//  - Q pre-scaled: p = exp2f(s) directly (32 fewer v_mul/iter)
//  - rowsum via ones-MFMA into lacc[16] (no 32-add serial chain; accL
//    atomics 1/row from lane lq==0)
//  - V^T staging as 4-row quad ushort4 (b64) writes -- identical vt layout
//    ((4q+i)^vswz == (4q)^vswz + i since vswz is a multiple of 8).
// ---------------------------------------------------------------------------
__global__ __launch_bounds__(128, 2) void r22_attn(const u16* __restrict__ Q,
                                                   const u16* __restrict__ K,
                                                   const u16* __restrict__ V,
                                                   float* __restrict__ accO,
                                                   float* __restrict__ accL) {
  const int bx = blockIdx.x;          // 0..959
  const int h = bx / 160;
  const int u = 159 - (bx - h * 160);
  int qt, kc;
  if (u < 16)      { qt = u;                      kc = 0; }
  else if (u < 48) { int v = u - 16; qt = 16 + (v >> 1); kc = v & 1; }
  else if (u < 96) { int v = u - 48; int q3 = v / 3; qt = 32 + q3; kc = v - 3 * q3; }
  else             { int v = u - 96; qt = 48 + (v >> 2); kc = v & 3; }
  const int rowmax = 64 * qt + 63;
  const int c0 = kc << 10;
  const bool islast = (c0 + 1024 > rowmax);
  const int cend = islast ? (rowmax + 1) : (c0 + 1024);
  const int niter = (cend - c0) >> 6;

  const int tid = threadIdx.x;
  const int wv = tid >> 6, l = tid & 63;
  const int lq = l & 31;
  const int hi = l >> 5;

  __shared__ u16 Ks[64][128];
  __shared__ u16 vt[128][72];

  const int c_ = tid & 31, cc = c_ * 4, g = tid >> 5;
  const int vswz = (c_ & 7) << 3;

  const int qr = qt * 64 + wv * 32;
  const int qrow = qr + lq;

  short8 ones;
#pragma unroll
  for (int i = 0; i < 8; i++) ones[i] = (short)0x3F80;  // bf16 1.0

  short8 qf[8];
  {
    const u16* qp = Q + (size_t)qrow * 768 + h * 128 + hi * 8;
#pragma unroll
    for (int s = 0; s < 8; s++) qf[s] = *(const short8*)(qp + s * 16);
  }
  f32x16 oacc[4] = {};
  f32x16 lacc = {};

  for (int kv = 0; kv < niter; kv++) {
    const int k0 = c0 + kv * 64;

#pragma unroll
    for (int i = 0; i < 8; i++) {
      int rbase = wv * 32 + i * 4;
      int row = rbase + (l >> 4);
      int blk = (l & 15) ^ (row & 7);
      lds_ld16(K + (size_t)(k0 + row) * 768 + h * 128 + blk * 8, &Ks[rbase][0]);
    }
    // V^T staging: 4-row quads, b64 writes (same layout as ushort2 version)
#pragma unroll
    for (int it = 0; it < 4; it++) {
      int quad = g + 4 * it;          // 0..15
      int r0 = 4 * quad;
      const u16* vp = V + (size_t)(k0 + r0) * 768 + h * 128 + cc;
      ushort4 v0 = *(const ushort4*)(vp);
      ushort4 v1 = *(const ushort4*)(vp + 768);
      ushort4 v2 = *(const ushort4*)(vp + 1536);
      ushort4 v3 = *(const ushort4*)(vp + 2304);
      int rs4 = r0 ^ vswz;
      ushort4 t4;
      t4.x = v0.x; t4.y = v1.x; t4.z = v2.x; t4.w = v3.x;
      *(ushort4*)&vt[cc + 0][rs4] = t4;
      t4.x = v0.y; t4.y = v1.y; t4.z = v2.y; t4.w = v3.y;
      *(ushort4*)&vt[cc + 1][rs4] = t4;
      t4.x = v0.z; t4.y = v1.z; t4.z = v2.z; t4.w = v3.z;
      *(ushort4*)&vt[cc + 2][rs4] = t4;
      t4.x = v0.w; t4.y = v1.w; t4.z = v2.w; t4.w = v3.w;
      *(ushort4*)&vt[cc + 3][rs4] = t4;
    }
    __syncthreads();

    f32x16 sac0 = {}, sac1 = {};
    __builtin_amdgcn_s_setprio(1);
    {
      const int r0_ = lq, r1_ = 32 + lq;
#pragma unroll
      for (int s = 0; s < 8; s++) {
        short8 kf0 = *(const short8*)(&Ks[r0_][((s * 2 + hi) ^ (r0_ & 7)) * 8]);
        sac0 = __builtin_amdgcn_mfma_f32_32x32x16_bf16(kf0, qf[s], sac0, 0, 0, 0);
      }
#pragma unroll
      for (int s = 0; s < 8; s++) {
        short8 kf1 = *(const short8*)(&Ks[r1_][((s * 2 + hi) ^ (r1_ & 7)) * 8]);
        sac1 = __builtin_amdgcn_mfma_f32_32x32x16_bf16(kf1, qf[s], sac1, 0, 0, 0);
      }
    }
    __builtin_amdgcn_s_setprio(0);

    // lane-local softmax: Q pre-scaled, so p = exp2(s) directly
    float p[32];
    const bool maskit = islast && (kv == niter - 1);
    if (maskit) {
#pragma unroll
      for (int r = 0; r < 16; r++) {
        int kvg = k0 + (r & 3) + 8 * (r >> 2) + 4 * hi;
        p[r] = (kvg <= qrow) ? exp2f(sac0[r]) : 0.0f;
      }
#pragma unroll
      for (int r = 0; r < 16; r++) {
        int kvg = k0 + 32 + (r & 3) + 8 * (r >> 2) + 4 * hi;
        p[16 + r] = (kvg <= qrow) ? exp2f(sac1[r]) : 0.0f;
      }
    } else {
#pragma unroll
      for (int r = 0; r < 16; r++) p[r] = exp2f(sac0[r]);
#pragma unroll
      for (int r = 0; r < 16; r++) p[16 + r] = exp2f(sac1[r]);
    }

    union { unsigned int w[4]; short8 v; } pa[4];
#pragma unroll
    for (int s = 0; s < 4; s++) {
      const int b = s * 8;
      unsigned int cA0 = cvtpk_bf16(p[b + 0], p[b + 1]);
      unsigned int cA1 = cvtpk_bf16(p[b + 2], p[b + 3]);
      unsigned int cB0 = cvtpk_bf16(p[b + 4], p[b + 5]);
      unsigned int cB1 = cvtpk_bf16(p[b + 6], p[b + 7]);
      u32x2 s0 = __builtin_amdgcn_permlane32_swap(cA0, cB0, false, false);
      u32x2 s1 = __builtin_amdgcn_permlane32_swap(cA1, cB1, false, false);
      pa[s].w[0] = s0[0]; pa[s].w[1] = s1[0]; pa[s].w[2] = s0[1]; pa[s].w[3] = s1[1];
    }

    __builtin_amdgcn_s_setprio(1);
    // rowsum via ones-MFMA (replaces 32 VALU adds)
#pragma unroll
    for (int s = 0; s < 4; s++)
      lacc = __builtin_amdgcn_mfma_f32_32x32x16_bf16(pa[s].v, ones, lacc, 0, 0, 0);
#pragma unroll
    for (int dt = 0; dt < 4; dt++) {
      const int d = dt * 32 + lq;
      const int dz = ((d >> 2) & 7) << 3;
#pragma unroll
      for (int s = 0; s < 4; s++) {
        short8 vf = *(const short8*)(&vt[d][(s * 16 + hi * 8) ^ dz]);
        oacc[dt] = __builtin_amdgcn_mfma_f32_32x32x16_bf16(pa[s].v, vf, oacc[dt], 0, 0, 0);
      }
    }
    __builtin_amdgcn_s_setprio(0);
    __syncthreads();
  }

#pragma unroll
  for (int dt = 0; dt < 4; dt++) {
    const int d = dt * 32 + lq;
#pragma unroll
    for (int r = 0; r < 16; r++) {
      int qrw = qr + (r & 3) + 8 * (r >> 2) + 4 * hi;
      unsafeAtomicAdd(&accO[(size_t)qrw * 768 + h * 128 + d], oacc[dt][r]);
    }
  }
  if (lq == 0) {
#pragma unroll
    for (int r = 0; r < 16; r++) {
      int qrw = qr + (r & 3) + 8 * (r >> 2) + 4 * hi;
      unsafeAtomicAdd(&accL[qrw * 6 + h], lacc[r]);
    }
  }
}

// ---------------------------------------------------------------------------
// d_out FLOAT32: out0 = y@Wo^T [3145728 f32], out1 = v_residual [3145728].
// Workspace (37.9 MB): xb@0, qb, kb, vb (u16), accO+accL (f32).
// Wq/Wk/Wv bf16 alias accO (dead before zeroing); Wo bf16 aliases xb.
// ---------------------------------------------------------------------------
extern "C" void kernel_launch(void* const* d_in, const int* in_sizes, int n_in,
                              void* d_out, int out_size, void* d_ws, size_t ws_size,
                              hipStream_t stream) {
  const float* x = (const float*)d_in[0];
  const float* vres = (const float*)d_in[1];
  const float* Wq = (const float*)d_in[2];
  const float* Wk = (const float*)d_in[3];
  const float* Wv = (const float*)d_in[4];
  const float* Wo = (const float*)d_in[5];
  const float* lamb = (const float*)d_in[6];
  const int* pos = (const int*)d_in[7];
  float* out = (float*)d_out;

  u16* xb = (u16*)d_ws;
  u16* qb = xb + 3145728;
  u16* kb = qb + 3145728;
  u16* vb = kb + 3145728;
  float* accO = (float*)((char*)d_ws + 25165824);
  float* accL = accO + 3145728;
  u16* wqb = (u16*)accO;
  u16* wkb = wqb + 589824;
  u16* wvb = wkb + 589824;
  u16* wob = xb;
  float* out1 = out + 3145728;

  r22_cvt<<<4800, 256, 0, stream>>>(x, Wq, Wk, Wv, xb, wqb, wkb, wvb);
  r22_gemm_qkv<<<dim3(64, 6, 3), 256, 0, stream>>>(xb, wqb, wkb, wvb, qb, kb, vb);
  r22_normrope<<<6144, 256, 0, stream>>>(qb, kb, vb, vres, lamb, pos, out1,
                                         accO, Wo, wob);
  r22_attn<<<960, 128, 0, stream>>>(qb, kb, vb, accO, accL);
  r22_gemm_proj<<<dim3(64, 6), 256, 0, stream>>>(accO, accL, wob, out);
}

// Round 23
// 140.040 us; speedup vs baseline: 1.5443x; 1.0043x over previous
//
#include <hip/hip_runtime.h>
#include <hip/hip_bf16.h>

typedef unsigned short u16;
typedef __attribute__((ext_vector_type(8))) short short8;
typedef __attribute__((ext_vector_type(4))) float f32x4;
typedef __attribute__((ext_vector_type(16))) float f32x16;
typedef __attribute__((ext_vector_type(2))) unsigned int u32x2;

#define MODEL 768
// 1/sqrt(128) * log2(e): exp(s/sqrt(128)) == exp2(s * SCALE2)
#define SCALE2 0.1275174137f

__device__ __forceinline__ float bf2f(u16 u) {
  unsigned int x = ((unsigned int)u) << 16;
  return __uint_as_float(x);
}
__device__ __forceinline__ u16 f2bf(float f) {
  unsigned int x = __float_as_uint(f);
  unsigned int r = (x + 0x7FFFu + ((x >> 16) & 1u)) >> 16;
  return (u16)r;
}
__device__ __forceinline__ void lds_ld16(const u16* g, u16* l) {
  __builtin_amdgcn_global_load_lds((const __attribute__((address_space(1))) void*)g,
                                   (__attribute__((address_space(3))) void*)l, 16, 0, 0);
}
__device__ __forceinline__ unsigned int cvtpk_bf16(float lo, float hi_) {
  unsigned int r;
  asm("v_cvt_pk_bf16_f32 %0, %1, %2" : "=v"(r) : "v"(lo), "v"(hi_));
  return r;
}

// ---------------------------------------------------------------------------
// Kernel 1 (r22-exact): convert x f32->bf16 AND Wq/Wk/Wv f32->bf16 into the
// accO region (dead until attn).  Grid 4800 x 256.
// ---------------------------------------------------------------------------
__global__ __launch_bounds__(256) void r23_cvt(const float* __restrict__ x,
                                               const float* __restrict__ wq,
                                               const float* __restrict__ wk,
                                               const float* __restrict__ wv,
                                               u16* __restrict__ xb,
                                               u16* __restrict__ wqb,
                                               u16* __restrict__ wkb,
                                               u16* __restrict__ wvb) {
  int i = blockIdx.x * 256 + threadIdx.x;
  const float* src;
  u16* dst;
  int j;
  if (i < 786432) { src = x; dst = xb; j = i; }
  else if (i < 933888) { src = wq; dst = wqb; j = i - 786432; }
  else if (i < 1081344) { src = wk; dst = wkb; j = i - 933888; }
  else { src = wv; dst = wvb; j = i - 1081344; }
  float4 v = ((const float4*)src)[j];
  ushort4 o;
  o.x = f2bf(v.x); o.y = f2bf(v.y); o.z = f2bf(v.z); o.w = f2bf(v.w);
  ((ushort4*)dst)[j] = o;
}

// ---------------------------------------------------------------------------
// GEMM QKV (r20-exact), 64-row tiles, all-gload_lds staging.
// ---------------------------------------------------------------------------
__global__ __launch_bounds__(256) void r23_gemm_qkv(const u16* __restrict__ A,
                                                    const u16* __restrict__ W0,
                                                    const u16* __restrict__ W1,
                                                    const u16* __restrict__ W2,
                                                    u16* __restrict__ C0,
                                                    u16* __restrict__ C1,
                                                    u16* __restrict__ C2) {
  const u16* Wb = (blockIdx.z == 0) ? W0 : (blockIdx.z == 1) ? W1 : W2;
  u16* C = (blockIdx.z == 0) ? C0 : (blockIdx.z == 1) ? C1 : C2;
  __shared__ u16 As[64 * 32];
  __shared__ u16 Bs[128 * 32];
  const int tid = threadIdx.x;
  const int w = tid >> 6, l = tid & 63;
  const int lr = l & 15, lg = l >> 4;
  const int m0 = blockIdx.x * 64, n0 = blockIdx.y * 128;
  const int wr = (w >> 1) * 32, wc = (w & 1) * 64;
  const int sr = w * 16 + (l >> 2);
  const int sc = (l & 3) * 8;
  f32x4 acc[2][4] = {};
  for (int k0 = 0; k0 < 768; k0 += 32) {
    __syncthreads();
    lds_ld16(A + (size_t)(m0 + sr) * 768 + k0 + sc, As + w * 512);
#pragma unroll
    for (int i = 0; i < 2; i++) {
      int ii = w * 2 + i;
      int row = ii * 16 + (l >> 2);
      lds_ld16(Wb + (size_t)(n0 + row) * 768 + k0 + sc, Bs + ii * 512);
    }
    __syncthreads();
    short8 af[2], bfr[4];
#pragma unroll
    for (int mr = 0; mr < 2; mr++) af[mr] = *(const short8*)(As + (wr + mr * 16 + lr) * 32 + lg * 8);
#pragma unroll
    for (int nc = 0; nc < 4; nc++) bfr[nc] = *(const short8*)(Bs + (wc + nc * 16 + lr) * 32 + lg * 8);
#pragma unroll
    for (int mr = 0; mr < 2; mr++)
#pragma unroll
      for (int nc = 0; nc < 4; nc++)
        acc[mr][nc] = __builtin_amdgcn_mfma_f32_16x16x32_bf16(af[mr], bfr[nc], acc[mr][nc], 0, 0, 0);
  }
#pragma unroll
  for (int mr = 0; mr < 2; mr++)
#pragma unroll
    for (int nc = 0; nc < 4; nc++)
#pragma unroll
      for (int ri = 0; ri < 4; ri++) {
        int row = m0 + wr + mr * 16 + lg * 4 + ri;
        int col = n0 + wc + nc * 16 + lr;
        C[(size_t)row * 768 + col] = f2bf(acc[mr][nc][ri]);
      }
}

// ---------------------------------------------------------------------------
// GEMM PROJ (r21-exact), 64-row tiles, bf16-W via gload_lds:
// A = accO/accL (fused finalize) staged f32->bf16; f32 out to d_out.
// ---------------------------------------------------------------------------
__global__ __launch_bounds__(256) void r23_gemm_proj(const float* __restrict__ accO,
                                                     const float* __restrict__ accL,
                                                     const u16* __restrict__ Wb,
                                                     float* __restrict__ C) {
  __shared__ u16 As[64 * 32];
  __shared__ u16 Bs[128 * 32];
  const int tid = threadIdx.x;
  const int w = tid >> 6, l = tid & 63;
  const int lr = l & 15, lg = l >> 4;
  const int m0 = blockIdx.x * 64, n0 = blockIdx.y * 128;
  const int wr = (w >> 1) * 32, wc = (w & 1) * 64;
  const int arow = tid >> 2;
  const int aoff = (tid & 3) * 8;
  const int sc = (l & 3) * 8;
  f32x4 acc[2][4] = {};
  for (int k0 = 0; k0 < 768; k0 += 32) {
    __syncthreads();
    {
      const float* ap = accO + (size_t)(m0 + arow) * 768 + k0 + aoff;
      float rl = 1.0f / accL[(m0 + arow) * 6 + (k0 >> 7)];
      u16* dp = As + arow * 32 + aoff;
      float4 f0 = ((const float4*)ap)[0];
      float4 f1 = ((const float4*)ap)[1];
      ushort4 b0, b1;
      b0.x = f2bf(f0.x * rl); b0.y = f2bf(f0.y * rl);
      b0.z = f2bf(f0.z * rl); b0.w = f2bf(f0.w * rl);
      b1.x = f2bf(f1.x * rl); b1.y = f2bf(f1.y * rl);
      b1.z = f2bf(f1.z * rl); b1.w = f2bf(f1.w * rl);
      *(ushort4*)(dp) = b0;
      *(ushort4*)(dp + 4) = b1;
    }
#pragma unroll
    for (int i = 0; i < 2; i++) {
      int ii = w * 2 + i;
      int row = ii * 16 + (l >> 2);
      lds_ld16(Wb + (size_t)(n0 + row) * 768 + k0 + sc, Bs + ii * 512);
    }
    __syncthreads();
    short8 af[2], bfr[4];
#pragma unroll
    for (int mr = 0; mr < 2; mr++) af[mr] = *(const short8*)(As + (wr + mr * 16 + lr) * 32 + lg * 8);
#pragma unroll
    for (int nc = 0; nc < 4; nc++) bfr[nc] = *(const short8*)(Bs + (wc + nc * 16 + lr) * 32 + lg * 8);
#pragma unroll
    for (int mr = 0; mr < 2; mr++)
#pragma unroll
      for (int nc = 0; nc < 4; nc++)
        acc[mr][nc] = __builtin_amdgcn_mfma_f32_16x16x32_bf16(af[mr], bfr[nc], acc[mr][nc], 0, 0, 0);
  }
#pragma unroll
  for (int mr = 0; mr < 2; mr++)
#pragma unroll
    for (int nc = 0; nc < 4; nc++)
#pragma unroll
      for (int ri = 0; ri < 4; ri++) {
        int row = m0 + wr + mr * 16 + lg * 4 + ri;
        int col = n0 + wc + nc * 16 + lr;
        C[(size_t)row * 768 + col] = acc[mr][nc][ri];
      }
}

// ---------------------------------------------------------------------------
// Kernel 3 (r22-exact): fused RMS-norm + rotary (Q,K; Q pre-scaled by
// SCALE2) + lambda-mix (V) + out1 copy + accO/accL zeroing + Wo cvt.
// ---------------------------------------------------------------------------
__global__ __launch_bounds__(256) void r23_normrope(u16* __restrict__ qb,
                                                    u16* __restrict__ kb,
                                                    u16* __restrict__ vb,
                                                    const float* __restrict__ vres,
                                                    const float* __restrict__ lambp,
                                                    const int* __restrict__ pos,
                                                    float* __restrict__ out1,
                                                    float* __restrict__ accZ,
                                                    const float* __restrict__ wo,
                                                    u16* __restrict__ wob) {
  {
    int gid = blockIdx.x * 256 + threadIdx.x;
    if (gid < 792576) {
      float4 z = {0.0f, 0.0f, 0.0f, 0.0f};
      ((float4*)accZ)[gid] = z;
    } else if (gid < 792576 + 147456) {
      int j = gid - 792576;
      float4 v = ((const float4*)wo)[j];
      ushort4 o;
      o.x = f2bf(v.x); o.y = f2bf(v.y); o.z = f2bf(v.z); o.w = f2bf(v.w);
      ((ushort4*)wob)[j] = o;
    }
  }
  const int wg = blockIdx.x * 4 + (threadIdx.x >> 6);
  const int l = threadIdx.x & 63;
  const int t = wg / 6;
  const int h = wg - t * 6;
  const size_t base = (size_t)t * MODEL + h * 128;
  const float EPS = 1.1920928955078125e-07f;

  float c = 1.0f, sn = 0.0f;
  if (l < 32) {
    float af = exp2f(-10.0f * (float)l * (1.0f / 31.0f));
    float th = (float)pos[t] * af;
    sincosf(th, &sn, &c);
  }
  {
    float a = bf2f(qb[base + l]), b = bf2f(qb[base + 64 + l]);
    float ss = a * a + b * b;
#pragma unroll
    for (int off = 32; off; off >>= 1) ss += __shfl_xor(ss, off);
    float r = rsqrtf(ss * (1.0f / 128.0f) + EPS) * SCALE2;
    float an = a * r, bn = b * r;
    qb[base + l] = f2bf(an * c + bn * sn);
    qb[base + 64 + l] = f2bf(bn * c - an * sn);
  }
  {
    float a = bf2f(kb[base + l]), b = bf2f(kb[base + 64 + l]);
    float ss = a * a + b * b;
#pragma unroll
    for (int off = 32; off; off >>= 1) ss += __shfl_xor(ss, off);
    float r = rsqrtf(ss * (1.0f / 128.0f) + EPS);
    float an = a * r, bn = b * r;
    kb[base + l] = f2bf(an * c + bn * sn);
    kb[base + 64 + l] = f2bf(bn * c - an * sn);
  }
  {
    float lm = *lambp;
    float a = bf2f(vb[base + l]), b = bf2f(vb[base + 64 + l]);
    float ra = vres[base + l], rb = vres[base + 64 + l];
    vb[base + l] = f2bf((1.0f - lm) * a + lm * ra);
    vb[base + 64 + l] = f2bf((1.0f - lm) * b + lm * rb);
    out1[base + l] = ra;
    out1[base + 64 + l] = rb;
  }
}

// ---------------------------------------------------------------------------
// Kernel 4: causal flash attention, 4-WAVE x 32 q-rows (128-row tasks),
// SPLIT-KV chunk 1024 (same atomic volume as r22; K/V fetch + staging
// instructions per wave HALVE vs 2-wave).  480 blocks longest-first.
// 32x32 MFMA swapped QK^T, in-register P, prescaled-Q static-max softmax,
// ones-MFMA rowsum, quad V^T writes, f32 hardware atomics.
// ---------------------------------------------------------------------------
__global__ __launch_bounds__(256, 2) void r23_attn(const u16* __restrict__ Q,
                                                   const u16* __restrict__ K,
                                                   const u16* __restrict__ V,
                                                   float* __restrict__ accO,
                                                   float* __restrict__ accL) {
  // decode: 80 tasks/head (qt 0..31, chunks of 1024), reversed -> longest first
  const int bx = blockIdx.x;          // 0..479
  const int h = bx / 80;
  const int u = 79 - (bx - h * 80);
  int qt, kc;
  if (u < 8)       { qt = u;                      kc = 0; }
  else if (u < 24) { int v = u - 8;  qt = 8 + (v >> 1); kc = v & 1; }
  else if (u < 48) { int v = u - 24; int q3 = v / 3; qt = 16 + q3; kc = v - 3 * q3; }
  else             { int v = u - 48; qt = 24 + (v >> 2); kc = v & 3; }
  const int rowmax = 128 * qt + 127;
  const int c0 = kc << 10;
  const bool islast = (c0 + 1024 > rowmax);
  const int cend = islast ? (rowmax + 1) : (c0 + 1024);
  const int niter = (cend - c0 + 63) >> 6;

  const int tid = threadIdx.x;
  const int wv = tid >> 6, l = tid & 63;
  const int lq = l & 31;
  const int hi = l >> 5;

  __shared__ u16 Ks[64][128];
  __shared__ u16 vt[128][72];

  const int c_ = tid & 31, cc = c_ * 4, g = tid >> 5;  // V-stage coords
  const int vswz = (c_ & 7) << 3;

  const int qr = qt * 128 + wv * 32;
  const int qrow = qr + lq;

  short8 ones;
#pragma unroll
  for (int i = 0; i < 8; i++) ones[i] = (short)0x3F80;  // bf16 1.0

  short8 qf[8];
  {
    const u16* qp = Q + (size_t)qrow * 768 + h * 128 + hi * 8;
#pragma unroll
    for (int s = 0; s < 8; s++) qf[s] = *(const short8*)(qp + s * 16);
  }
  f32x16 oacc[4] = {};
  f32x16 lacc = {};

  for (int kv = 0; kv < niter; kv++) {
    const int k0 = c0 + kv * 64;

    // K staging: 4 waves x 4 issues x 4 rows = 64 rows
#pragma unroll
    for (int i = 0; i < 4; i++) {
      int rbase = wv * 16 + i * 4;
      int row = rbase + (l >> 4);
      int blk = (l & 15) ^ (row & 7);
      lds_ld16(K + (size_t)(k0 + row) * 768 + h * 128 + blk * 8, &Ks[rbase][0]);
    }
    // V^T staging: 16 quads over 256 threads (2 per thread), b64 writes
#pragma unroll
    for (int it = 0; it < 2; it++) {
      int quad = g + 8 * it;          // 0..15
      int r0 = 4 * quad;
      const u16* vp = V + (size_t)(k0 + r0) * 768 + h * 128 + cc;
      ushort4 v0 = *(const ushort4*)(vp);
      ushort4 v1 = *(const ushort4*)(vp + 768);
      ushort4 v2 = *(const ushort4*)(vp + 1536);
      ushort4 v3 = *(const ushort4*)(vp + 2304);
      int rs4 = r0 ^ vswz;
      ushort4 t4;
      t4.x = v0.x; t4.y = v1.x; t4.z = v2.x; t4.w = v3.x;
      *(ushort4*)&vt[cc + 0][rs4] = t4;
      t4.x = v0.y; t4.y = v1.y; t4.z = v2.y; t4.w = v3.y;
      *(ushort4*)&vt[cc + 1][rs4] = t4;
      t4.x = v0.z; t4.y = v1.z; t4.z = v2.z; t4.w = v3.z;
      *(ushort4*)&vt[cc + 2][rs4] = t4;
      t4.x = v0.w; t4.y = v1.w; t4.z = v2.w; t4.w = v3.w;
      *(ushort4*)&vt[cc + 3][rs4] = t4;
    }
    __syncthreads();

    f32x16 sac0 = {}, sac1 = {};
    __builtin_amdgcn_s_setprio(1);
    {
      const int r0_ = lq, r1_ = 32 + lq;
#pragma unroll
      for (int s = 0; s < 8; s++) {
        short8 kf0 = *(const short8*)(&Ks[r0_][((s * 2 + hi) ^ (r0_ & 7)) * 8]);
        sac0 = __builtin_amdgcn_mfma_f32_32x32x16_bf16(kf0, qf[s], sac0, 0, 0, 0);
      }
#pragma unroll
      for (int s = 0; s < 8; s++) {
        short8 kf1 = *(const short8*)(&Ks[r1_][((s * 2 + hi) ^ (r1_ & 7)) * 8]);
        sac1 = __builtin_amdgcn_mfma_f32_32x32x16_bf16(kf1, qf[s], sac1, 0, 0, 0);
      }
    }
    __builtin_amdgcn_s_setprio(0);

    // lane-local softmax (Q pre-scaled): p = exp2(s)
    float p[32];
    const bool maskit = islast && (k0 + 63 > qr);
    if (maskit) {
#pragma unroll
      for (int r = 0; r < 16; r++) {
        int kvg = k0 + (r & 3) + 8 * (r >> 2) + 4 * hi;
        p[r] = (kvg <= qrow) ? exp2f(sac0[r]) : 0.0f;
      }
#pragma unroll
      for (int r = 0; r < 16; r++) {
        int kvg = k0 + 32 + (r & 3) + 8 * (r >> 2) + 4 * hi;
        p[16 + r] = (kvg <= qrow) ? exp2f(sac1[r]) : 0.0f;
      }
    } else {
#pragma unroll
      for (int r = 0; r < 16; r++) p[r] = exp2f(sac0[r]);
#pragma unroll
      for (int r = 0; r < 16; r++) p[16 + r] = exp2f(sac1[r]);
    }

    union { unsigned int w[4]; short8 v; } pa[4];
#pragma unroll
    for (int s = 0; s < 4; s++) {
      const int b = s * 8;
      unsigned int cA0 = cvtpk_bf16(p[b + 0], p[b + 1]);
      unsigned int cA1 = cvtpk_bf16(p[b + 2], p[b + 3]);
      unsigned int cB0 = cvtpk_bf16(p[b + 4], p[b + 5]);
      unsigned int cB1 = cvtpk_bf16(p[b + 6], p[b + 7]);
      u32x2 s0 = __builtin_amdgcn_permlane32_swap(cA0, cB0, false, false);
      u32x2 s1 = __builtin_amdgcn_permlane32_swap(cA1, cB1, false, false);
      pa[s].w[0] = s0[0]; pa[s].w[1] = s1[0]; pa[s].w[2] = s0[1]; pa[s].w[3] = s1[1];
    }

    __builtin_amdgcn_s_setprio(1);
#pragma unroll
    for (int s = 0; s < 4; s++)
      lacc = __builtin_amdgcn_mfma_f32_32x32x16_bf16(pa[s].v, ones, lacc, 0, 0, 0);
#pragma unroll
    for (int dt = 0; dt < 4; dt++) {
      const int d = dt * 32 + lq;
      const int dz = ((d >> 2) & 7) << 3;
#pragma unroll
      for (int s = 0; s < 4; s++) {
        short8 vf = *(const short8*)(&vt[d][(s * 16 + hi * 8) ^ dz]);
        oacc[dt] = __builtin_amdgcn_mfma_f32_32x32x16_bf16(pa[s].v, vf, oacc[dt], 0, 0, 0);
      }
    }
    __builtin_amdgcn_s_setprio(0);
    __syncthreads();
  }

#pragma unroll
  for (int dt = 0; dt < 4; dt++) {
    const int d = dt * 32 + lq;
#pragma unroll
    for (int r = 0; r < 16; r++) {
      int qrw = qr + (r & 3) + 8 * (r >> 2) + 4 * hi;
      unsafeAtomicAdd(&accO[(size_t)qrw * 768 + h * 128 + d], oacc[dt][r]);
    }
  }
  if (lq == 0) {
#pragma unroll
    for (int r = 0; r < 16; r++) {
      int qrw = qr + (r & 3) + 8 * (r >> 2) + 4 * hi;
      unsafeAtomicAdd(&accL[qrw * 6 + h], lacc[r]);
    }
  }
}

// ---------------------------------------------------------------------------
// d_out FLOAT32: out0 = y@Wo^T [3145728 f32], out1 = v_residual [3145728].
// Workspace (37.9 MB): xb@0, qb, kb, vb (u16), accO+accL (f32).
// Wq/Wk/Wv bf16 alias accO (dead before zeroing); Wo bf16 aliases xb.
// ---------------------------------------------------------------------------
extern "C" void kernel_launch(void* const* d_in, const int* in_sizes, int n_in,
                              void* d_out, int out_size, void* d_ws, size_t ws_size,
                              hipStream_t stream) {
  const float* x = (const float*)d_in[0];
  const float* vres = (const float*)d_in[1];
  const float* Wq = (const float*)d_in[2];
  const float* Wk = (const float*)d_in[3];
  const float* Wv = (const float*)d_in[4];
  const float* Wo = (const float*)d_in[5];
  const float* lamb = (const float*)d_in[6];
  const int* pos = (const int*)d_in[7];
  float* out = (float*)d_out;

  u16* xb = (u16*)d_ws;
  u16* qb = xb + 3145728;
  u16* kb = qb + 3145728;
  u16* vb = kb + 3145728;
  float* accO = (float*)((char*)d_ws + 25165824);
  float* accL = accO + 3145728;
  u16* wqb = (u16*)accO;
  u16* wkb = wqb + 589824;
  u16* wvb = wkb + 589824;
  u16* wob = xb;
  float* out1 = out + 3145728;

  r23_cvt<<<4800, 256, 0, stream>>>(x, Wq, Wk, Wv, xb, wqb, wkb, wvb);
  r23_gemm_qkv<<<dim3(64, 6, 3), 256, 0, stream>>>(xb, wqb, wkb, wvb, qb, kb, vb);
  r23_normrope<<<6144, 256, 0, stream>>>(qb, kb, vb, vres, lamb, pos, out1,
                                         accO, Wo, wob);
  r23_attn<<<480, 256, 0, stream>>>(qb, kb, vb, accO, accL);
  r23_gemm_proj<<<dim3(64, 6), 256, 0, stream>>>(accO, accL, wob, out);
}

// Round 24
// 129.656 us; speedup vs baseline: 1.6680x; 1.0801x over previous
//
#include <hip/hip_runtime.h>
#include <hip/hip_bf16.h>

typedef unsigned short u16;
typedef __attribute__((ext_vector_type(8))) short short8;
typedef __attribute__((ext_vector_type(4))) float f32x4;
typedef __attribute__((ext_vector_type(16))) float f32x16;
typedef __attribute__((ext_vector_type(2))) unsigned int u32x2;

#define MODEL 768
// 1/sqrt(128) * log2(e): exp(s/sqrt(128)) == exp2(s * SCALE2)
#define SCALE2 0.1275174137f

__device__ __forceinline__ float bf2f(u16 u) {
  unsigned int x = ((unsigned int)u) << 16;
  return __uint_as_float(x);
}
__device__ __forceinline__ u16 f2bf(float f) {
  unsigned int x = __float_as_uint(f);
  unsigned int r = (x + 0x7FFFu + ((x >> 16) & 1u)) >> 16;
  return (u16)r;
}
__device__ __forceinline__ void lds_ld16(const u16* g, u16* l) {
  __builtin_amdgcn_global_load_lds((const __attribute__((address_space(1))) void*)g,
                                   (__attribute__((address_space(3))) void*)l, 16, 0, 0);
}
__device__ __forceinline__ unsigned int cvtpk_bf16(float lo, float hi_) {
  unsigned int r;
  asm("v_cvt_pk_bf16_f32 %0, %1, %2" : "=v"(r) : "v"(lo), "v"(hi_));
  return r;
}

// ---------------------------------------------------------------------------
// Kernel 1 (r23-exact): convert x f32->bf16 AND Wq/Wk/Wv f32->bf16 into the
// accO region (dead until attn).  Grid 4800 x 256.
// ---------------------------------------------------------------------------
__global__ __launch_bounds__(256) void r24_cvt(const float* __restrict__ x,
                                               const float* __restrict__ wq,
                                               const float* __restrict__ wk,
                                               const float* __restrict__ wv,
                                               u16* __restrict__ xb,
                                               u16* __restrict__ wqb,
                                               u16* __restrict__ wkb,
                                               u16* __restrict__ wvb) {
  int i = blockIdx.x * 256 + threadIdx.x;
  const float* src;
  u16* dst;
  int j;
  if (i < 786432) { src = x; dst = xb; j = i; }
  else if (i < 933888) { src = wq; dst = wqb; j = i - 786432; }
  else if (i < 1081344) { src = wk; dst = wkb; j = i - 933888; }
  else { src = wv; dst = wvb; j = i - 1081344; }
  float4 v = ((const float4*)src)[j];
  ushort4 o;
  o.x = f2bf(v.x); o.y = f2bf(v.y); o.z = f2bf(v.z); o.w = f2bf(v.w);
  ((ushort4*)dst)[j] = o;
}

// ---------------------------------------------------------------------------
// GEMM QKV, 64-row tiles, BK=64 (12 K-iters, half the barrier drains).
// All-gload_lds staging, 8-rows/issue, source swizzle blk=(l&7)^(row&7).
// LDS 24 KB.  Grid (64,6,3) = 1152 blocks.
// ---------------------------------------------------------------------------
__global__ __launch_bounds__(256) void r24_gemm_qkv(const u16* __restrict__ A,
                                                    const u16* __restrict__ W0,
                                                    const u16* __restrict__ W1,
                                                    const u16* __restrict__ W2,
                                                    u16* __restrict__ C0,
                                                    u16* __restrict__ C1,
                                                    u16* __restrict__ C2) {
  const u16* Wb = (blockIdx.z == 0) ? W0 : (blockIdx.z == 1) ? W1 : W2;
  u16* C = (blockIdx.z == 0) ? C0 : (blockIdx.z == 1) ? C1 : C2;
  __shared__ u16 As[64 * 64];    // 8 KB
  __shared__ u16 Bs[128 * 64];   // 16 KB
  const int tid = threadIdx.x;
  const int w = tid >> 6, l = tid & 63;
  const int lr = l & 15, lg = l >> 4;
  const int m0 = blockIdx.x * 64, n0 = blockIdx.y * 128;
  const int wr = (w >> 1) * 32, wc = (w & 1) * 64;
  const int srow = l >> 3;       // 0..7 row within 8-row issue group
  const int sblk = l & 7;        // col-block slot 0..7
  f32x4 acc[2][4] = {};
  for (int k0 = 0; k0 < 768; k0 += 64) {
    __syncthreads();
    // A: 8 issues (2/wave), rows ii*8..+7
#pragma unroll
    for (int i = 0; i < 2; i++) {
      int ii = w * 2 + i;
      int row = ii * 8 + srow;
      int blk = sblk ^ (row & 7);
      lds_ld16(A + (size_t)(m0 + row) * 768 + k0 + blk * 8, As + ii * 512);
    }
    // B: 16 issues (4/wave)
#pragma unroll
    for (int i = 0; i < 4; i++) {
      int ii = w * 4 + i;
      int row = ii * 8 + srow;
      int blk = sblk ^ (row & 7);
      lds_ld16(Wb + (size_t)(n0 + row) * 768 + k0 + blk * 8, Bs + ii * 512);
    }
    __syncthreads();
#pragma unroll
    for (int kk = 0; kk < 2; kk++) {
      short8 af[2], bfr[4];
#pragma unroll
      for (int mr = 0; mr < 2; mr++) {
        int r = wr + mr * 16 + lr;
        af[mr] = *(const short8*)(As + r * 64 + (((kk * 4 + lg) ^ (r & 7)) * 8));
      }
#pragma unroll
      for (int nc = 0; nc < 4; nc++) {
        int r = wc + nc * 16 + lr;
        bfr[nc] = *(const short8*)(Bs + r * 64 + (((kk * 4 + lg) ^ (r & 7)) * 8));
      }
#pragma unroll
      for (int mr = 0; mr < 2; mr++)
#pragma unroll
        for (int nc = 0; nc < 4; nc++)
          acc[mr][nc] = __builtin_amdgcn_mfma_f32_16x16x32_bf16(af[mr], bfr[nc], acc[mr][nc], 0, 0, 0);
    }
  }
#pragma unroll
  for (int mr = 0; mr < 2; mr++)
#pragma unroll
    for (int nc = 0; nc < 4; nc++)
#pragma unroll
      for (int ri = 0; ri < 4; ri++) {
        int row = m0 + wr + mr * 16 + lg * 4 + ri;
        int col = n0 + wc + nc * 16 + lr;
        C[(size_t)row * 768 + col] = f2bf(acc[mr][nc][ri]);
      }
}

// ---------------------------------------------------------------------------
// GEMM PROJ, 64-row tiles, BK=64: A = accO/accL (fused finalize) staged
// f32->bf16 into swizzled layout; W bf16 via gload_lds; f32 out to d_out.
// ---------------------------------------------------------------------------
__global__ __launch_bounds__(256) void r24_gemm_proj(const float* __restrict__ accO,
                                                     const float* __restrict__ accL,
                                                     const u16* __restrict__ Wb,
                                                     float* __restrict__ C) {
  __shared__ u16 As[64 * 64];
  __shared__ u16 Bs[128 * 64];
  const int tid = threadIdx.x;
  const int w = tid >> 6, l = tid & 63;
  const int lr = l & 15, lg = l >> 4;
  const int m0 = blockIdx.x * 64, n0 = blockIdx.y * 128;
  const int wr = (w >> 1) * 32, wc = (w & 1) * 64;
  const int arow = tid >> 2;         // 0..63
  const int ab0 = (tid & 3) * 2;     // first of two 8-col blocks
  const int srow = l >> 3;
  const int sblk = l & 7;
  f32x4 acc[2][4] = {};
  for (int k0 = 0; k0 < 768; k0 += 64) {
    __syncthreads();
    {
      const float* ap = accO + (size_t)(m0 + arow) * 768 + k0 + ab0 * 8;
      float rl = 1.0f / accL[(m0 + arow) * 6 + (k0 >> 7)];
      float4 f0 = ((const float4*)ap)[0];
      float4 f1 = ((const float4*)ap)[1];
      float4 f2 = ((const float4*)ap)[2];
      float4 f3 = ((const float4*)ap)[3];
      union { ushort4 u4[2]; short8 v; } p0, p1;
      p0.u4[0].x = f2bf(f0.x * rl); p0.u4[0].y = f2bf(f0.y * rl);
      p0.u4[0].z = f2bf(f0.z * rl); p0.u4[0].w = f2bf(f0.w * rl);
      p0.u4[1].x = f2bf(f1.x * rl); p0.u4[1].y = f2bf(f1.y * rl);
      p0.u4[1].z = f2bf(f1.z * rl); p0.u4[1].w = f2bf(f1.w * rl);
      p1.u4[0].x = f2bf(f2.x * rl); p1.u4[0].y = f2bf(f2.y * rl);
      p1.u4[0].z = f2bf(f2.z * rl); p1.u4[0].w = f2bf(f2.w * rl);
      p1.u4[1].x = f2bf(f3.x * rl); p1.u4[1].y = f2bf(f3.y * rl);
      p1.u4[1].z = f2bf(f3.z * rl); p1.u4[1].w = f2bf(f3.w * rl);
      *(short8*)(As + arow * 64 + ((ab0 ^ (arow & 7)) * 8)) = p0.v;
      *(short8*)(As + arow * 64 + (((ab0 + 1) ^ (arow & 7)) * 8)) = p1.v;
    }
#pragma unroll
    for (int i = 0; i < 4; i++) {
      int ii = w * 4 + i;
      int row = ii * 8 + srow;
      int blk = sblk ^ (row & 7);
      lds_ld16(Wb + (size_t)(n0 + row) * 768 + k0 + blk * 8, Bs + ii * 512);
    }
    __syncthreads();
#pragma unroll
    for (int kk = 0; kk < 2; kk++) {
      short8 af[2], bfr[4];
#pragma unroll
      for (int mr = 0; mr < 2; mr++) {
        int r = wr + mr * 16 + lr;
        af[mr] = *(const short8*)(As + r * 64 + (((kk * 4 + lg) ^ (r & 7)) * 8));
      }
#pragma unroll
      for (int nc = 0; nc < 4; nc++) {
        int r = wc + nc * 16 + lr;
        bfr[nc] = *(const short8*)(Bs + r * 64 + (((kk * 4 + lg) ^ (r & 7)) * 8));
      }
#pragma unroll
      for (int mr = 0; mr < 2; mr++)
#pragma unroll
        for (int nc = 0; nc < 4; nc++)
          acc[mr][nc] = __builtin_amdgcn_mfma_f32_16x16x32_bf16(af[mr], bfr[nc], acc[mr][nc], 0, 0, 0);
    }
  }
#pragma unroll
  for (int mr = 0; mr < 2; mr++)
#pragma unroll
    for (int nc = 0; nc < 4; nc++)
#pragma unroll
      for (int ri = 0; ri < 4; ri++) {
        int row = m0 + wr + mr * 16 + lg * 4 + ri;
        int col = n0 + wc + nc * 16 + lr;
        C[(size_t)row * 768 + col] = acc[mr][nc][ri];
      }
}

// ---------------------------------------------------------------------------
// Kernel 3 (r23-exact): fused RMS-norm + rotary (Q,K; Q pre-scaled by
// SCALE2) + lambda-mix (V) + out1 copy + accO/accL zeroing + Wo cvt.
// ---------------------------------------------------------------------------
__global__ __launch_bounds__(256) void r24_normrope(u16* __restrict__ qb,
                                                    u16* __restrict__ kb,
                                                    u16* __restrict__ vb,
                                                    const float* __restrict__ vres,
                                                    const float* __restrict__ lambp,
                                                    const int* __restrict__ pos,
                                                    float* __restrict__ out1,
                                                    float* __restrict__ accZ,
                                                    const float* __restrict__ wo,
                                                    u16* __restrict__ wob) {
  {
    int gid = blockIdx.x * 256 + threadIdx.x;
    if (gid < 792576) {
      float4 z = {0.0f, 0.0f, 0.0f, 0.0f};
      ((float4*)accZ)[gid] = z;
    } else if (gid < 792576 + 147456) {
      int j = gid - 792576;
      float4 v = ((const float4*)wo)[j];
      ushort4 o;
      o.x = f2bf(v.x); o.y = f2bf(v.y); o.z = f2bf(v.z); o.w = f2bf(v.w);
      ((ushort4*)wob)[j] = o;
    }
  }
  const int wg = blockIdx.x * 4 + (threadIdx.x >> 6);
  const int l = threadIdx.x & 63;
  const int t = wg / 6;
  const int h = wg - t * 6;
  const size_t base = (size_t)t * MODEL + h * 128;
  const float EPS = 1.1920928955078125e-07f;

  float c = 1.0f, sn = 0.0f;
  if (l < 32) {
    float af = exp2f(-10.0f * (float)l * (1.0f / 31.0f));
    float th = (float)pos[t] * af;
    sincosf(th, &sn, &c);
  }
  {
    float a = bf2f(qb[base + l]), b = bf2f(qb[base + 64 + l]);
    float ss = a * a + b * b;
#pragma unroll
    for (int off = 32; off; off >>= 1) ss += __shfl_xor(ss, off);
    float r = rsqrtf(ss * (1.0f / 128.0f) + EPS) * SCALE2;
    float an = a * r, bn = b * r;
    qb[base + l] = f2bf(an * c + bn * sn);
    qb[base + 64 + l] = f2bf(bn * c - an * sn);
  }
  {
    float a = bf2f(kb[base + l]), b = bf2f(kb[base + 64 + l]);
    float ss = a * a + b * b;
#pragma unroll
    for (int off = 32; off; off >>= 1) ss += __shfl_xor(ss, off);
    float r = rsqrtf(ss * (1.0f / 128.0f) + EPS);
    float an = a * r, bn = b * r;
    kb[base + l] = f2bf(an * c + bn * sn);
    kb[base + 64 + l] = f2bf(bn * c - an * sn);
  }
  {
    float lm = *lambp;
    float a = bf2f(vb[base + l]), b = bf2f(vb[base + 64 + l]);
    float ra = vres[base + l], rb = vres[base + 64 + l];
    vb[base + l] = f2bf((1.0f - lm) * a + lm * ra);
    vb[base + 64 + l] = f2bf((1.0f - lm) * b + lm * rb);
    out1[base + l] = ra;
    out1[base + 64 + l] = rb;
  }
}

// ---------------------------------------------------------------------------
// Kernel 4 (r23-exact): causal flash attention, 4-wave x 32 q-rows,
// SPLIT-KV chunk 1024, 480 blocks longest-first, 32x32 MFMA swapped QK^T,
// in-register P, prescaled-Q static-max softmax, ones-MFMA rowsum,
// quad V^T writes, f32 hardware atomics.
// ---------------------------------------------------------------------------
__global__ __launch_bounds__(256, 2) void r24_attn(const u16* __restrict__ Q,
                                                   const u16* __restrict__ K,
                                                   const u16* __restrict__ V,
                                                   float* __restrict__ accO,
                                                   float* __restrict__ accL) {
  const int bx = blockIdx.x;          // 0..479
  const int h = bx / 80;
  const int u = 79 - (bx - h * 80);
  int qt, kc;
  if (u < 8)       { qt = u;                      kc = 0; }
  else if (u < 24) { int v = u - 8;  qt = 8 + (v >> 1); kc = v & 1; }
  else if (u < 48) { int v = u - 24; int q3 = v / 3; qt = 16 + q3; kc = v - 3 * q3; }
  else             { int v = u - 48; qt = 24 + (v >> 2); kc = v & 3; }
  const int rowmax = 128 * qt + 127;
  const int c0 = kc << 10;
  const bool islast = (c0 + 1024 > rowmax);
  const int cend = islast ? (rowmax + 1) : (c0 + 1024);
  const int niter = (cend - c0 + 63) >> 6;

  const int tid = threadIdx.x;
  const int wv = tid >> 6, l = tid & 63;
  const int lq = l & 31;
  const int hi = l >> 5;

  __shared__ u16 Ks[64][128];
  __shared__ u16 vt[128][72];

  const int c_ = tid & 31, cc = c_ * 4, g = tid >> 5;
  const int vswz = (c_ & 7) << 3;

  const int qr = qt * 128 + wv * 32;
  const int qrow = qr + lq;

  short8 ones;
#pragma unroll
  for (int i = 0; i < 8; i++) ones[i] = (short)0x3F80;  // bf16 1.0

  short8 qf[8];
  {
    const u16* qp = Q + (size_t)qrow * 768 + h * 128 + hi * 8;
#pragma unroll
    for (int s = 0; s < 8; s++) qf[s] = *(const short8*)(qp + s * 16);
  }
  f32x16 oacc[4] = {};
  f32x16 lacc = {};

  for (int kv = 0; kv < niter; kv++) {
    const int k0 = c0 + kv * 64;

#pragma unroll
    for (int i = 0; i < 4; i++) {
      int rbase = wv * 16 + i * 4;
      int row = rbase + (l >> 4);
      int blk = (l & 15) ^ (row & 7);
      lds_ld16(K + (size_t)(k0 + row) * 768 + h * 128 + blk * 8, &Ks[rbase][0]);
    }
#pragma unroll
    for (int it = 0; it < 2; it++) {
      int quad = g + 8 * it;
      int r0 = 4 * quad;
      const u16* vp = V + (size_t)(k0 + r0) * 768 + h * 128 + cc;
      ushort4 v0 = *(const ushort4*)(vp);
      ushort4 v1 = *(const ushort4*)(vp + 768);
      ushort4 v2 = *(const ushort4*)(vp + 1536);
      ushort4 v3 = *(const ushort4*)(vp + 2304);
      int rs4 = r0 ^ vswz;
      ushort4 t4;
      t4.x = v0.x; t4.y = v1.x; t4.z = v2.x; t4.w = v3.x;
      *(ushort4*)&vt[cc + 0][rs4] = t4;
      t4.x = v0.y; t4.y = v1.y; t4.z = v2.y; t4.w = v3.y;
      *(ushort4*)&vt[cc + 1][rs4] = t4;
      t4.x = v0.z; t4.y = v1.z; t4.z = v2.z; t4.w = v3.z;
      *(ushort4*)&vt[cc + 2][rs4] = t4;
      t4.x = v0.w; t4.y = v1.w; t4.z = v2.w; t4.w = v3.w;
      *(ushort4*)&vt[cc + 3][rs4] = t4;
    }
    __syncthreads();

    f32x16 sac0 = {}, sac1 = {};
    __builtin_amdgcn_s_setprio(1);
    {
      const int r0_ = lq, r1_ = 32 + lq;
#pragma unroll
      for (int s = 0; s < 8; s++) {
        short8 kf0 = *(const short8*)(&Ks[r0_][((s * 2 + hi) ^ (r0_ & 7)) * 8]);
        sac0 = __builtin_amdgcn_mfma_f32_32x32x16_bf16(kf0, qf[s], sac0, 0, 0, 0);
      }
#pragma unroll
      for (int s = 0; s < 8; s++) {
        short8 kf1 = *(const short8*)(&Ks[r1_][((s * 2 + hi) ^ (r1_ & 7)) * 8]);
        sac1 = __builtin_amdgcn_mfma_f32_32x32x16_bf16(kf1, qf[s], sac1, 0, 0, 0);
      }
    }
    __builtin_amdgcn_s_setprio(0);

    float p[32];
    const bool maskit = islast && (k0 + 63 > qr);
    if (maskit) {
#pragma unroll
      for (int r = 0; r < 16; r++) {
        int kvg = k0 + (r & 3) + 8 * (r >> 2) + 4 * hi;
        p[r] = (kvg <= qrow) ? exp2f(sac0[r]) : 0.0f;
      }
#pragma unroll
      for (int r = 0; r < 16; r++) {
        int kvg = k0 + 32 + (r & 3) + 8 * (r >> 2) + 4 * hi;
        p[16 + r] = (kvg <= qrow) ? exp2f(sac1[r]) : 0.0f;
      }
    } else {
#pragma unroll
      for (int r = 0; r < 16; r++) p[r] = exp2f(sac0[r]);
#pragma unroll
      for (int r = 0; r < 16; r++) p[16 + r] = exp2f(sac1[r]);
    }

    union { unsigned int w[4]; short8 v; } pa[4];
#pragma unroll
    for (int s = 0; s < 4; s++) {
      const int b = s * 8;
      unsigned int cA0 = cvtpk_bf16(p[b + 0], p[b + 1]);
      unsigned int cA1 = cvtpk_bf16(p[b + 2], p[b + 3]);
      unsigned int cB0 = cvtpk_bf16(p[b + 4], p[b + 5]);
      unsigned int cB1 = cvtpk_bf16(p[b + 6], p[b + 7]);
      u32x2 s0 = __builtin_amdgcn_permlane32_swap(cA0, cB0, false, false);
      u32x2 s1 = __builtin_amdgcn_permlane32_swap(cA1, cB1, false, false);
      pa[s].w[0] = s0[0]; pa[s].w[1] = s1[0]; pa[s].w[2] = s0[1]; pa[s].w[3] = s1[1];
    }

    __builtin_amdgcn_s_setprio(1);
#pragma unroll
    for (int s = 0; s < 4; s++)
      lacc = __builtin_amdgcn_mfma_f32_32x32x16_bf16(pa[s].v, ones, lacc, 0, 0, 0);
#pragma unroll
    for (int dt = 0; dt < 4; dt++) {
      const int d = dt * 32 + lq;
      const int dz = ((d >> 2) & 7) << 3;
#pragma unroll
      for (int s = 0; s < 4; s++) {
        short8 vf = *(const short8*)(&vt[d][(s * 16 + hi * 8) ^ dz]);
        oacc[dt] = __builtin_amdgcn_mfma_f32_32x32x16_bf16(pa[s].v, vf, oacc[dt], 0, 0, 0);
      }
    }
    __builtin_amdgcn_s_setprio(0);
    __syncthreads();
  }

#pragma unroll
  for (int dt = 0; dt < 4; dt++) {
    const int d = dt * 32 + lq;
#pragma unroll
    for (int r = 0; r < 16; r++) {
      int qrw = qr + (r & 3) + 8 * (r >> 2) + 4 * hi;
      unsafeAtomicAdd(&accO[(size_t)qrw * 768 + h * 128 + d], oacc[dt][r]);
    }
  }
  if (lq == 0) {
#pragma unroll
    for (int r = 0; r < 16; r++) {
      int qrw = qr + (r & 3) + 8 * (r >> 2) + 4 * hi;
      unsafeAtomicAdd(&accL[qrw * 6 + h], lacc[r]);
    }
  }
}

// ---------------------------------------------------------------------------
// d_out FLOAT32: out0 = y@Wo^T [3145728 f32], out1 = v_residual [3145728].
// Workspace (37.9 MB): xb@0, qb, kb, vb (u16), accO+accL (f32).
// Wq/Wk/Wv bf16 alias accO (dead before zeroing); Wo bf16 aliases xb.
// ---------------------------------------------------------------------------
extern "C" void kernel_launch(void* const* d_in, const int* in_sizes, int n_in,
                              void* d_out, int out_size, void* d_ws, size_t ws_size,
                              hipStream_t stream) {
  const float* x = (const float*)d_in[0];
  const float* vres = (const float*)d_in[1];
  const float* Wq = (const float*)d_in[2];
  const float* Wk = (const float*)d_in[3];
  const float* Wv = (const float*)d_in[4];
  const float* Wo = (const float*)d_in[5];
  const float* lamb = (const float*)d_in[6];
  const int* pos = (const int*)d_in[7];
  float* out = (float*)d_out;

  u16* xb = (u16*)d_ws;
  u16* qb = xb + 3145728;
  u16* kb = qb + 3145728;
  u16* vb = kb + 3145728;
  float* accO = (float*)((char*)d_ws + 25165824);
  float* accL = accO + 3145728;
  u16* wqb = (u16*)accO;
  u16* wkb = wqb + 589824;
  u16* wvb = wkb + 589824;
  u16* wob = xb;
  float* out1 = out + 3145728;

  r24_cvt<<<4800, 256, 0, stream>>>(x, Wq, Wk, Wv, xb, wqb, wkb, wvb);
  r24_gemm_qkv<<<dim3(64, 6, 3), 256, 0, stream>>>(xb, wqb, wkb, wvb, qb, kb, vb);
  r24_normrope<<<6144, 256, 0, stream>>>(qb, kb, vb, vres, lamb, pos, out1,
                                         accO, Wo, wob);
  r24_attn<<<480, 256, 0, stream>>>(qb, kb, vb, accO, accL);
  r24_gemm_proj<<<dim3(64, 6), 256, 0, stream>>>(accO, accL, wob, out);
}

// Round 25
// 126.147 us; speedup vs baseline: 1.7144x; 1.0278x over previous
//
#include <hip/hip_runtime.h>
#include <hip/hip_bf16.h>

typedef unsigned short u16;
typedef __attribute__((ext_vector_type(8))) short short8;
typedef __attribute__((ext_vector_type(4))) float f32x4;
typedef __attribute__((ext_vector_type(16))) float f32x16;
typedef __attribute__((ext_vector_type(2))) unsigned int u32x2;

#define MODEL 768
// 1/sqrt(128) * log2(e): exp(s/sqrt(128)) == exp2(s * SCALE2)
#define SCALE2 0.1275174137f

__device__ __forceinline__ float bf2f(u16 u) {
  unsigned int x = ((unsigned int)u) << 16;
  return __uint_as_float(x);
}
__device__ __forceinline__ u16 f2bf(float f) {
  unsigned int x = __float_as_uint(f);
  unsigned int r = (x + 0x7FFFu + ((x >> 16) & 1u)) >> 16;
  return (u16)r;
}
__device__ __forceinline__ void lds_ld16(const u16* g, u16* l) {
  __builtin_amdgcn_global_load_lds((const __attribute__((address_space(1))) void*)g,
                                   (__attribute__((address_space(3))) void*)l, 16, 0, 0);
}
__device__ __forceinline__ unsigned int cvtpk_bf16(float lo, float hi_) {
  unsigned int r;
  asm("v_cvt_pk_bf16_f32 %0, %1, %2" : "=v"(r) : "v"(lo), "v"(hi_));
  return r;
}

// ---------------------------------------------------------------------------
// Kernel 1 (r24-exact): convert x f32->bf16 AND Wq/Wk/Wv f32->bf16 into the
// accO region (dead until attn).  Grid 4800 x 256.
// ---------------------------------------------------------------------------
__global__ __launch_bounds__(256) void r25_cvt(const float* __restrict__ x,
                                               const float* __restrict__ wq,
                                               const float* __restrict__ wk,
                                               const float* __restrict__ wv,
                                               u16* __restrict__ xb,
                                               u16* __restrict__ wqb,
                                               u16* __restrict__ wkb,
                                               u16* __restrict__ wvb) {
  int i = blockIdx.x * 256 + threadIdx.x;
  const float* src;
  u16* dst;
  int j;
  if (i < 786432) { src = x; dst = xb; j = i; }
  else if (i < 933888) { src = wq; dst = wqb; j = i - 786432; }
  else if (i < 1081344) { src = wk; dst = wkb; j = i - 933888; }
  else { src = wv; dst = wvb; j = i - 1081344; }
  float4 v = ((const float4*)src)[j];
  ushort4 o;
  o.x = f2bf(v.x); o.y = f2bf(v.y); o.z = f2bf(v.z); o.w = f2bf(v.w);
  ((ushort4*)dst)[j] = o;
}

// ---------------------------------------------------------------------------
// GEMM QKV (r24-exact), 64-row tiles, BK=64, all-gload_lds staging.
// ---------------------------------------------------------------------------
__global__ __launch_bounds__(256) void r25_gemm_qkv(const u16* __restrict__ A,
                                                    const u16* __restrict__ W0,
                                                    const u16* __restrict__ W1,
                                                    const u16* __restrict__ W2,
                                                    u16* __restrict__ C0,
                                                    u16* __restrict__ C1,
                                                    u16* __restrict__ C2) {
  const u16* Wb = (blockIdx.z == 0) ? W0 : (blockIdx.z == 1) ? W1 : W2;
  u16* C = (blockIdx.z == 0) ? C0 : (blockIdx.z == 1) ? C1 : C2;
  __shared__ u16 As[64 * 64];
  __shared__ u16 Bs[128 * 64];
  const int tid = threadIdx.x;
  const int w = tid >> 6, l = tid & 63;
  const int lr = l & 15, lg = l >> 4;
  const int m0 = blockIdx.x * 64, n0 = blockIdx.y * 128;
  const int wr = (w >> 1) * 32, wc = (w & 1) * 64;
  const int srow = l >> 3;
  const int sblk = l & 7;
  f32x4 acc[2][4] = {};
  for (int k0 = 0; k0 < 768; k0 += 64) {
    __syncthreads();
#pragma unroll
    for (int i = 0; i < 2; i++) {
      int ii = w * 2 + i;
      int row = ii * 8 + srow;
      int blk = sblk ^ (row & 7);
      lds_ld16(A + (size_t)(m0 + row) * 768 + k0 + blk * 8, As + ii * 512);
    }
#pragma unroll
    for (int i = 0; i < 4; i++) {
      int ii = w * 4 + i;
      int row = ii * 8 + srow;
      int blk = sblk ^ (row & 7);
      lds_ld16(Wb + (size_t)(n0 + row) * 768 + k0 + blk * 8, Bs + ii * 512);
    }
    __syncthreads();
#pragma unroll
    for (int kk = 0; kk < 2; kk++) {
      short8 af[2], bfr[4];
#pragma unroll
      for (int mr = 0; mr < 2; mr++) {
        int r = wr + mr * 16 + lr;
        af[mr] = *(const short8*)(As + r * 64 + (((kk * 4 + lg) ^ (r & 7)) * 8));
      }
#pragma unroll
      for (int nc = 0; nc < 4; nc++) {
        int r = wc + nc * 16 + lr;
        bfr[nc] = *(const short8*)(Bs + r * 64 + (((kk * 4 + lg) ^ (r & 7)) * 8));
      }
#pragma unroll
      for (int mr = 0; mr < 2; mr++)
#pragma unroll
        for (int nc = 0; nc < 4; nc++)
          acc[mr][nc] = __builtin_amdgcn_mfma_f32_16x16x32_bf16(af[mr], bfr[nc], acc[mr][nc], 0, 0, 0);
    }
  }
#pragma unroll
  for (int mr = 0; mr < 2; mr++)
#pragma unroll
    for (int nc = 0; nc < 4; nc++)
#pragma unroll
      for (int ri = 0; ri < 4; ri++) {
        int row = m0 + wr + mr * 16 + lg * 4 + ri;
        int col = n0 + wc + nc * 16 + lr;
        C[(size_t)row * 768 + col] = f2bf(acc[mr][nc][ri]);
      }
}

// ---------------------------------------------------------------------------
// GEMM PROJ (r24-exact), 64-row tiles, BK=64, fused finalize.
// ---------------------------------------------------------------------------
__global__ __launch_bounds__(256) void r25_gemm_proj(const float* __restrict__ accO,
                                                     const float* __restrict__ accL,
                                                     const u16* __restrict__ Wb,
                                                     float* __restrict__ C) {
  __shared__ u16 As[64 * 64];
  __shared__ u16 Bs[128 * 64];
  const int tid = threadIdx.x;
  const int w = tid >> 6, l = tid & 63;
  const int lr = l & 15, lg = l >> 4;
  const int m0 = blockIdx.x * 64, n0 = blockIdx.y * 128;
  const int wr = (w >> 1) * 32, wc = (w & 1) * 64;
  const int arow = tid >> 2;
  const int ab0 = (tid & 3) * 2;
  const int srow = l >> 3;
  const int sblk = l & 7;
  f32x4 acc[2][4] = {};
  for (int k0 = 0; k0 < 768; k0 += 64) {
    __syncthreads();
    {
      const float* ap = accO + (size_t)(m0 + arow) * 768 + k0 + ab0 * 8;
      float rl = 1.0f / accL[(m0 + arow) * 6 + (k0 >> 7)];
      float4 f0 = ((const float4*)ap)[0];
      float4 f1 = ((const float4*)ap)[1];
      float4 f2 = ((const float4*)ap)[2];
      float4 f3 = ((const float4*)ap)[3];
      union { ushort4 u4[2]; short8 v; } p0, p1;
      p0.u4[0].x = f2bf(f0.x * rl); p0.u4[0].y = f2bf(f0.y * rl);
      p0.u4[0].z = f2bf(f0.z * rl); p0.u4[0].w = f2bf(f0.w * rl);
      p0.u4[1].x = f2bf(f1.x * rl); p0.u4[1].y = f2bf(f1.y * rl);
      p0.u4[1].z = f2bf(f1.z * rl); p0.u4[1].w = f2bf(f1.w * rl);
      p1.u4[0].x = f2bf(f2.x * rl); p1.u4[0].y = f2bf(f2.y * rl);
      p1.u4[0].z = f2bf(f2.z * rl); p1.u4[0].w = f2bf(f2.w * rl);
      p1.u4[1].x = f2bf(f3.x * rl); p1.u4[1].y = f2bf(f3.y * rl);
      p1.u4[1].z = f2bf(f3.z * rl); p1.u4[1].w = f2bf(f3.w * rl);
      *(short8*)(As + arow * 64 + ((ab0 ^ (arow & 7)) * 8)) = p0.v;
      *(short8*)(As + arow * 64 + (((ab0 + 1) ^ (arow & 7)) * 8)) = p1.v;
    }
#pragma unroll
    for (int i = 0; i < 4; i++) {
      int ii = w * 4 + i;
      int row = ii * 8 + srow;
      int blk = sblk ^ (row & 7);
      lds_ld16(Wb + (size_t)(n0 + row) * 768 + k0 + blk * 8, Bs + ii * 512);
    }
    __syncthreads();
#pragma unroll
    for (int kk = 0; kk < 2; kk++) {
      short8 af[2], bfr[4];
#pragma unroll
      for (int mr = 0; mr < 2; mr++) {
        int r = wr + mr * 16 + lr;
        af[mr] = *(const short8*)(As + r * 64 + (((kk * 4 + lg) ^ (r & 7)) * 8));
      }
#pragma unroll
      for (int nc = 0; nc < 4; nc++) {
        int r = wc + nc * 16 + lr;
        bfr[nc] = *(const short8*)(Bs + r * 64 + (((kk * 4 + lg) ^ (r & 7)) * 8));
      }
#pragma unroll
      for (int mr = 0; mr < 2; mr++)
#pragma unroll
        for (int nc = 0; nc < 4; nc++)
          acc[mr][nc] = __builtin_amdgcn_mfma_f32_16x16x32_bf16(af[mr], bfr[nc], acc[mr][nc], 0, 0, 0);
    }
  }
#pragma unroll
  for (int mr = 0; mr < 2; mr++)
#pragma unroll
    for (int nc = 0; nc < 4; nc++)
#pragma unroll
      for (int ri = 0; ri < 4; ri++) {
        int row = m0 + wr + mr * 16 + lg * 4 + ri;
        int col = n0 + wc + nc * 16 + lr;
        C[(size_t)row * 768 + col] = acc[mr][nc][ri];
      }
}

// ---------------------------------------------------------------------------
// Kernel 3 (r24-exact): fused RMS-norm + rotary (Q pre-scaled) + V mix
// + out1 copy + accO/accL zeroing + Wo cvt.
// ---------------------------------------------------------------------------
__global__ __launch_bounds__(256) void r25_normrope(u16* __restrict__ qb,
                                                    u16* __restrict__ kb,
                                                    u16* __restrict__ vb,
                                                    const float* __restrict__ vres,
                                                    const float* __restrict__ lambp,
                                                    const int* __restrict__ pos,
                                                    float* __restrict__ out1,
                                                    float* __restrict__ accZ,
                                                    const float* __restrict__ wo,
                                                    u16* __restrict__ wob) {
  {
    int gid = blockIdx.x * 256 + threadIdx.x;
    if (gid < 792576) {
      float4 z = {0.0f, 0.0f, 0.0f, 0.0f};
      ((float4*)accZ)[gid] = z;
    } else if (gid < 792576 + 147456) {
      int j = gid - 792576;
      float4 v = ((const float4*)wo)[j];
      ushort4 o;
      o.x = f2bf(v.x); o.y = f2bf(v.y); o.z = f2bf(v.z); o.w = f2bf(v.w);
      ((ushort4*)wob)[j] = o;
    }
  }
  const int wg = blockIdx.x * 4 + (threadIdx.x >> 6);
  const int l = threadIdx.x & 63;
  const int t = wg / 6;
  const int h = wg - t * 6;
  const size_t base = (size_t)t * MODEL + h * 128;
  const float EPS = 1.1920928955078125e-07f;

  float c = 1.0f, sn = 0.0f;
  if (l < 32) {
    float af = exp2f(-10.0f * (float)l * (1.0f / 31.0f));
    float th = (float)pos[t] * af;
    sincosf(th, &sn, &c);
  }
  {
    float a = bf2f(qb[base + l]), b = bf2f(qb[base + 64 + l]);
    float ss = a * a + b * b;
#pragma unroll
    for (int off = 32; off; off >>= 1) ss += __shfl_xor(ss, off);
    float r = rsqrtf(ss * (1.0f / 128.0f) + EPS) * SCALE2;
    float an = a * r, bn = b * r;
    qb[base + l] = f2bf(an * c + bn * sn);
    qb[base + 64 + l] = f2bf(bn * c - an * sn);
  }
  {
    float a = bf2f(kb[base + l]), b = bf2f(kb[base + 64 + l]);
    float ss = a * a + b * b;
#pragma unroll
    for (int off = 32; off; off >>= 1) ss += __shfl_xor(ss, off);
    float r = rsqrtf(ss * (1.0f / 128.0f) + EPS);
    float an = a * r, bn = b * r;
    kb[base + l] = f2bf(an * c + bn * sn);
    kb[base + 64 + l] = f2bf(bn * c - an * sn);
  }
  {
    float lm = *lambp;
    float a = bf2f(vb[base + l]), b = bf2f(vb[base + 64 + l]);
    float ra = vres[base + l], rb = vres[base + 64 + l];
    vb[base + l] = f2bf((1.0f - lm) * a + lm * ra);
    vb[base + 64 + l] = f2bf((1.0f - lm) * b + lm * rb);
    out1[base + l] = ra;
    out1[base + 64 + l] = rb;
  }
}

// ---------------------------------------------------------------------------
// Kernel 4: causal flash attention, 4-wave x 32 q-rows, chunk 1024,
// 480 blocks longest-first.  r25: DOUBLE-BUFFERED Ks AND vt with a single
// barrier per iteration -- K(i+1) gload_lds and V(i+1) reg-loads issue at
// iter top and fly under QK/softmax/PV; V regs write vt[nxt] (last read
// a barrier ago) before the barrier.  LDS 68KB; grid 1.9 blocks/CU so
// 2-blocks/CU capacity loses nothing (fixes r15's occupancy mistake).
// ---------------------------------------------------------------------------
__global__ __launch_bounds__(256, 2) void r25_attn(const u16* __restrict__ Q,
                                                   const u16* __restrict__ K,
                                                   const u16* __restrict__ V,
                                                   float* __restrict__ accO,
                                                   float* __restrict__ accL) {
  const int bx = blockIdx.x;          // 0..479
  const int h = bx / 80;
  const int u = 79 - (bx - h * 80);
  int qt, kc;
  if (u < 8)       { qt = u;                      kc = 0; }
  else if (u < 24) { int v = u - 8;  qt = 8 + (v >> 1); kc = v & 1; }
  else if (u < 48) { int v = u - 24; int q3 = v / 3; qt = 16 + q3; kc = v - 3 * q3; }
  else             { int v = u - 48; qt = 24 + (v >> 2); kc = v & 3; }
  const int rowmax = 128 * qt + 127;
  const int c0 = kc << 10;
  const bool islast = (c0 + 1024 > rowmax);
  const int cend = islast ? (rowmax + 1) : (c0 + 1024);
  const int niter = (cend - c0 + 63) >> 6;

  const int tid = threadIdx.x;
  const int wv = tid >> 6, l = tid & 63;
  const int lq = l & 31;
  const int hi = l >> 5;

  __shared__ u16 Ks[2][64][128];   // 32 KB
  __shared__ u16 vt[2][128][72];   // 36 KB

  const int c_ = tid & 31, cc = c_ * 4, g = tid >> 5;
  const int vswz = (c_ & 7) << 3;

  const int qr = qt * 128 + wv * 32;
  const int qrow = qr + lq;

  short8 ones;
#pragma unroll
  for (int i = 0; i < 8; i++) ones[i] = (short)0x3F80;  // bf16 1.0

  short8 qf[8];
  {
    const u16* qp = Q + (size_t)qrow * 768 + h * 128 + hi * 8;
#pragma unroll
    for (int s = 0; s < 8; s++) qf[s] = *(const short8*)(qp + s * 16);
  }
  f32x16 oacc[4] = {};
  f32x16 lacc = {};

  // ---- prologue: stage tile 0 (K -> Ks[0], V -> vt[0]) ----
#pragma unroll
  for (int i = 0; i < 4; i++) {
    int rbase = wv * 16 + i * 4;
    int row = rbase + (l >> 4);
    int blk = (l & 15) ^ (row & 7);
    lds_ld16(K + (size_t)(c0 + row) * 768 + h * 128 + blk * 8, &Ks[0][rbase][0]);
  }
#pragma unroll
  for (int it = 0; it < 2; it++) {
    int quad = g + 8 * it;
    int r0 = 4 * quad;
    const u16* vp = V + (size_t)(c0 + r0) * 768 + h * 128 + cc;
    ushort4 v0 = *(const ushort4*)(vp);
    ushort4 v1 = *(const ushort4*)(vp + 768);
    ushort4 v2 = *(const ushort4*)(vp + 1536);
    ushort4 v3 = *(const ushort4*)(vp + 2304);
    int rs4 = r0 ^ vswz;
    ushort4 t4;
    t4.x = v0.x; t4.y = v1.x; t4.z = v2.x; t4.w = v3.x;
    *(ushort4*)&vt[0][cc + 0][rs4] = t4;
    t4.x = v0.y; t4.y = v1.y; t4.z = v2.y; t4.w = v3.y;
    *(ushort4*)&vt[0][cc + 1][rs4] = t4;
    t4.x = v0.z; t4.y = v1.z; t4.z = v2.z; t4.w = v3.z;
    *(ushort4*)&vt[0][cc + 2][rs4] = t4;
    t4.x = v0.w; t4.y = v1.w; t4.z = v2.w; t4.w = v3.w;
    *(ushort4*)&vt[0][cc + 3][rs4] = t4;
  }
  __syncthreads();

  for (int kv = 0; kv < niter; kv++) {
    const int cur = kv & 1, nxt = cur ^ 1;
    const int k0 = c0 + kv * 64;
    const bool pre = (kv + 1 < niter);

    // ---- issue next-tile staging (flies under QK/softmax/PV) ----
    ushort4 vr[2][4];
    if (pre) {
      const int k0n = k0 + 64;
#pragma unroll
      for (int i = 0; i < 4; i++) {
        int rbase = wv * 16 + i * 4;
        int row = rbase + (l >> 4);
        int blk = (l & 15) ^ (row & 7);
        lds_ld16(K + (size_t)(k0n + row) * 768 + h * 128 + blk * 8, &Ks[nxt][rbase][0]);
      }
#pragma unroll
      for (int it = 0; it < 2; it++) {
        int r0 = 4 * (g + 8 * it);
        const u16* vp = V + (size_t)(k0n + r0) * 768 + h * 128 + cc;
        vr[it][0] = *(const ushort4*)(vp);
        vr[it][1] = *(const ushort4*)(vp + 768);
        vr[it][2] = *(const ushort4*)(vp + 1536);
        vr[it][3] = *(const ushort4*)(vp + 2304);
      }
    }

    // ---- S^T = K Q^T from Ks[cur] ----
    f32x16 sac0 = {}, sac1 = {};
    __builtin_amdgcn_s_setprio(1);
    {
      const int r0_ = lq, r1_ = 32 + lq;
#pragma unroll
      for (int s = 0; s < 8; s++) {
        short8 kf0 = *(const short8*)(&Ks[cur][r0_][((s * 2 + hi) ^ (r0_ & 7)) * 8]);
        sac0 = __builtin_amdgcn_mfma_f32_32x32x16_bf16(kf0, qf[s], sac0, 0, 0, 0);
      }
#pragma unroll
      for (int s = 0; s < 8; s++) {
        short8 kf1 = *(const short8*)(&Ks[cur][r1_][((s * 2 + hi) ^ (r1_ & 7)) * 8]);
        sac1 = __builtin_amdgcn_mfma_f32_32x32x16_bf16(kf1, qf[s], sac1, 0, 0, 0);
      }
    }
    __builtin_amdgcn_s_setprio(0);

    // ---- lane-local softmax (Q pre-scaled) ----
    float p[32];
    const bool maskit = islast && (k0 + 63 > qr);
    if (maskit) {
#pragma unroll
      for (int r = 0; r < 16; r++) {
        int kvg = k0 + (r & 3) + 8 * (r >> 2) + 4 * hi;
        p[r] = (kvg <= qrow) ? exp2f(sac0[r]) : 0.0f;
      }
#pragma unroll
      for (int r = 0; r < 16; r++) {
        int kvg = k0 + 32 + (r & 3) + 8 * (r >> 2) + 4 * hi;
        p[16 + r] = (kvg <= qrow) ? exp2f(sac1[r]) : 0.0f;
      }
    } else {
#pragma unroll
      for (int r = 0; r < 16; r++) p[r] = exp2f(sac0[r]);
#pragma unroll
      for (int r = 0; r < 16; r++) p[16 + r] = exp2f(sac1[r]);
    }

    union { unsigned int w[4]; short8 v; } pa[4];
#pragma unroll
    for (int s = 0; s < 4; s++) {
      const int b = s * 8;
      unsigned int cA0 = cvtpk_bf16(p[b + 0], p[b + 1]);
      unsigned int cA1 = cvtpk_bf16(p[b + 2], p[b + 3]);
      unsigned int cB0 = cvtpk_bf16(p[b + 4], p[b + 5]);
      unsigned int cB1 = cvtpk_bf16(p[b + 6], p[b + 7]);
      u32x2 s0 = __builtin_amdgcn_permlane32_swap(cA0, cB0, false, false);
      u32x2 s1 = __builtin_amdgcn_permlane32_swap(cA1, cB1, false, false);
      pa[s].w[0] = s0[0]; pa[s].w[1] = s1[0]; pa[s].w[2] = s0[1]; pa[s].w[3] = s1[1];
    }

    __builtin_amdgcn_s_setprio(1);
#pragma unroll
    for (int s = 0; s < 4; s++)
      lacc = __builtin_amdgcn_mfma_f32_32x32x16_bf16(pa[s].v, ones, lacc, 0, 0, 0);
#pragma unroll
    for (int dt = 0; dt < 4; dt++) {
      const int d = dt * 32 + lq;
      const int dz = ((d >> 2) & 7) << 3;
#pragma unroll
      for (int s = 0; s < 4; s++) {
        short8 vf = *(const short8*)(&vt[cur][d][(s * 16 + hi * 8) ^ dz]);
        oacc[dt] = __builtin_amdgcn_mfma_f32_32x32x16_bf16(pa[s].v, vf, oacc[dt], 0, 0, 0);
      }
    }
    __builtin_amdgcn_s_setprio(0);

    // ---- write V(i+1) regs -> vt[nxt] (safe: last read a barrier ago) ----
    if (pre) {
#pragma unroll
      for (int it = 0; it < 2; it++) {
        int r0 = 4 * (g + 8 * it);
        int rs4 = r0 ^ vswz;
        ushort4 t4;
        t4.x = vr[it][0].x; t4.y = vr[it][1].x; t4.z = vr[it][2].x; t4.w = vr[it][3].x;
        *(ushort4*)&vt[nxt][cc + 0][rs4] = t4;
        t4.x = vr[it][0].y; t4.y = vr[it][1].y; t4.z = vr[it][2].y; t4.w = vr[it][3].y;
        *(ushort4*)&vt[nxt][cc + 1][rs4] = t4;
        t4.x = vr[it][0].z; t4.y = vr[it][1].z; t4.z = vr[it][2].z; t4.w = vr[it][3].z;
        *(ushort4*)&vt[nxt][cc + 2][rs4] = t4;
        t4.x = vr[it][0].w; t4.y = vr[it][1].w; t4.z = vr[it][2].w; t4.w = vr[it][3].w;
        *(ushort4*)&vt[nxt][cc + 3][rs4] = t4;
      }
    }
    __syncthreads();   // drains vmcnt (Ks[nxt] ready) + lgkm (vt[nxt] ready);
                       // all waves done reading Ks[cur]/vt[cur]
  }

#pragma unroll
  for (int dt = 0; dt < 4; dt++) {
    const int d = dt * 32 + lq;
#pragma unroll
    for (int r = 0; r < 16; r++) {
      int qrw = qr + (r & 3) + 8 * (r >> 2) + 4 * hi;
      unsafeAtomicAdd(&accO[(size_t)qrw * 768 + h * 128 + d], oacc[dt][r]);
    }
  }
  if (lq == 0) {
#pragma unroll
    for (int r = 0; r < 16; r++) {
      int qrw = qr + (r & 3) + 8 * (r >> 2) + 4 * hi;
      unsafeAtomicAdd(&accL[qrw * 6 + h], lacc[r]);
    }
  }
}

// ---------------------------------------------------------------------------
// d_out FLOAT32: out0 = y@Wo^T [3145728 f32], out1 = v_residual [3145728].
// Workspace (37.9 MB): xb@0, qb, kb, vb (u16), accO+accL (f32).
// Wq/Wk/Wv bf16 alias accO (dead before zeroing); Wo bf16 aliases xb.
// ---------------------------------------------------------------------------
extern "C" void kernel_launch(void* const* d_in, const int* in_sizes, int n_in,
                              void* d_out, int out_size, void* d_ws, size_t ws_size,
                              hipStream_t stream) {
  const float* x = (const float*)d_in[0];
  const float* vres = (const float*)d_in[1];
  const float* Wq = (const float*)d_in[2];
  const float* Wk = (const float*)d_in[3];
  const float* Wv = (const float*)d_in[4];
  const float* Wo = (const float*)d_in[5];
  const float* lamb = (const float*)d_in[6];
  const int* pos = (const int*)d_in[7];
  float* out = (float*)d_out;

  u16* xb = (u16*)d_ws;
  u16* qb = xb + 3145728;
  u16* kb = qb + 3145728;
  u16* vb = kb + 3145728;
  float* accO = (float*)((char*)d_ws + 25165824);
  float* accL = accO + 3145728;
  u16* wqb = (u16*)accO;
  u16* wkb = wqb + 589824;
  u16* wvb = wkb + 589824;
  u16* wob = xb;
  float* out1 = out + 3145728;

  r25_cvt<<<4800, 256, 0, stream>>>(x, Wq, Wk, Wv, xb, wqb, wkb, wvb);
  r25_gemm_qkv<<<dim3(64, 6, 3), 256, 0, stream>>>(xb, wqb, wkb, wvb, qb, kb, vb);
  r25_normrope<<<6144, 256, 0, stream>>>(qb, kb, vb, vres, lamb, pos, out1,
                                         accO, Wo, wob);
  r25_attn<<<480, 256, 0, stream>>>(qb, kb, vb, accO, accL);
  r25_gemm_proj<<<dim3(64, 6), 256, 0, stream>>>(accO, accL, wob, out);
}